// Round 4
// baseline (547.427 us; speedup 1.0000x reference)
//
#include <hip/hip_runtime.h>
#include <cstdint>
#include <cstddef>

typedef __attribute__((ext_vector_type(4))) float f32x4;
typedef __attribute__((ext_vector_type(8))) short bf16x8;

#define S_LEN 2048
#define HDIM 4096
#define QKVD 6144
#define NHEAD 32
#define NKVH 8
#define HD 128
#define ATT_SCALE 0.08838834764831845f

// fp32 -> bf16 RNE (finite inputs only)
__device__ __forceinline__ short f2bf(float f) {
  unsigned int u = __float_as_uint(f);
  u += 0x7FFFu + ((u >> 16) & 1u);
  return (short)(u >> 16);
}

// async global->LDS, 16B per lane. LDS dest = wave-uniform base + lane*16.
__device__ __forceinline__ void gl_lds16(const short* g, short* l) {
  __builtin_amdgcn_global_load_lds((const __attribute__((address_space(1))) void*)g,
                                   (__attribute__((address_space(3))) void*)l,
                                   16, 0, 0);
}

__global__ void cvt_kernel(const float* __restrict__ in, short* __restrict__ out, int n) {
  int i = (blockIdx.x * blockDim.x + threadIdx.x) * 4;
  if (i >= n) return;
  const float4 v = *reinterpret_cast<const float4*>(in + i);
  short4 o;
  o.x = f2bf(v.x); o.y = f2bf(v.y); o.z = f2bf(v.z); o.w = f2bf(v.w);
  *reinterpret_cast<short4*>(out + i) = o;
}

// C[M][N] = A[M][K] * B[N][K]^T (bf16 in, fp32 out), 128x128 tile, BK=32,
// m97 structure: global_load_lds width=16, 2 barriers per K-step.
__global__ __launch_bounds__(256) void gemm_lds(const short* __restrict__ A,
                                                const short* __restrict__ B,
                                                float* __restrict__ C,
                                                int M, int N, int K) {
  __shared__ short lA[128 * 32];
  __shared__ short lB[128 * 32];
  const int t = threadIdx.x;
  const int w = t >> 6, lane = t & 63;
  const int l15 = lane & 15, l4 = lane >> 4;
  const int tm = blockIdx.y * 128, tn = blockIdx.x * 128;
  const int wr = (w >> 1) * 64, wc = (w & 1) * 64;

  const int c0 = w * 128 + lane, c1 = c0 + 64;
  const short* gA0 = A + (size_t)(tm + (c0 >> 2)) * K + (c0 & 3) * 8;
  const short* gA1 = A + (size_t)(tm + (c1 >> 2)) * K + (c1 & 3) * 8;
  const short* gB0 = B + (size_t)(tn + (c0 >> 2)) * K + (c0 & 3) * 8;
  const short* gB1 = B + (size_t)(tn + (c1 >> 2)) * K + (c1 & 3) * 8;
  short* lA0 = lA + c0 * 8; short* lA1 = lA + c1 * 8;
  short* lB0 = lB + c0 * 8; short* lB1 = lB + c1 * 8;

  f32x4 acc[4][4] = {};

  for (int k0 = 0; k0 < K; k0 += 32) {
    gl_lds16(gA0 + k0, lA0);
    gl_lds16(gA1 + k0, lA1);
    gl_lds16(gB0 + k0, lB0);
    gl_lds16(gB1 + k0, lB1);
    __syncthreads();
    bf16x8 af[4], bfr[4];
#pragma unroll
    for (int m = 0; m < 4; ++m)
      af[m] = *reinterpret_cast<const bf16x8*>(lA + (wr + m * 16 + l15) * 32 + l4 * 8);
#pragma unroll
    for (int n = 0; n < 4; ++n)
      bfr[n] = *reinterpret_cast<const bf16x8*>(lB + (wc + n * 16 + l15) * 32 + l4 * 8);
#pragma unroll
    for (int m = 0; m < 4; ++m)
#pragma unroll
      for (int n = 0; n < 4; ++n)
        acc[m][n] = __builtin_amdgcn_mfma_f32_16x16x32_bf16(af[m], bfr[n], acc[m][n], 0, 0, 0);
    __syncthreads();
  }
#pragma unroll
  for (int m = 0; m < 4; ++m)
#pragma unroll
    for (int n = 0; n < 4; ++n)
#pragma unroll
      for (int r = 0; r < 4; ++r) {
        int rr = tm + wr + m * 16 + l4 * 4 + r;
        int cc = tn + wc + n * 16 + l15;
        C[(size_t)rr * N + cc] = acc[m][n][r];
      }
}

// qkv fp32 [S][6144] -> roped bf16 Q[NH][S][HD], K[NKV][S][HD], V[NKV][S][HD]
__global__ void rope_kernel(const float* __restrict__ qkv,
                            const float* __restrict__ cb,
                            const float* __restrict__ sb,
                            short* __restrict__ Q,
                            short* __restrict__ Kx,
                            short* __restrict__ V) {
  int tid = blockIdx.x * blockDim.x + threadIdx.x;
  int s = tid / QKVD;
  int j = tid - s * QKVD;
  int g = j / 768;
  int idx = j - g * 768;
  float val = qkv[tid];
  if (idx < 640) {
    int part = idx >> 7;  // 0..3 = q heads in group, 4 = k
    int d = idx & 127;
    int d2 = (d < 64) ? d + 64 : d - 64;
    float pv = qkv[(size_t)s * QKVD + g * 768 + part * 128 + d2];
    float c = cb[s * HD + d], sn = sb[s * HD + d];
    float ov = (d < 64) ? (val * c - pv * sn) : (val * c + pv * sn);
    if (part < 4) {
      int hh = g * 4 + part;
      Q[((size_t)hh * S_LEN + s) * HD + d] = f2bf(ov);
    } else {
      Kx[((size_t)g * S_LEN + s) * HD + d] = f2bf(ov);
    }
  } else {
    int d = idx - 640;
    V[((size_t)g * S_LEN + s) * HD + d] = f2bf(val);
  }
}

// V [NKVH][S][HD] -> Vt [NKVH][HD][S], 64x64 LDS tiles, coalesced both sides
__global__ __launch_bounds__(256) void vtrans_kernel(const short* __restrict__ V,
                                                     short* __restrict__ Vt) {
  __shared__ short tile[64][72];
  const int kvh = blockIdx.z;
  const int s0 = blockIdx.x * 64, d0 = blockIdx.y * 64;
  const int t = threadIdx.x;
  const short* Vb = V + (size_t)kvh * S_LEN * HD;
  short* Vtb = Vt + (size_t)kvh * HD * S_LEN;
#pragma unroll
  for (int i = 0; i < 2; ++i) {
    int sl = i * 32 + (t >> 3), dl = (t & 7) * 8;
    bf16x8 v = *reinterpret_cast<const bf16x8*>(Vb + (size_t)(s0 + sl) * HD + d0 + dl);
    *reinterpret_cast<bf16x8*>(&tile[sl][dl]) = v;
  }
  __syncthreads();
#pragma unroll
  for (int i = 0; i < 2; ++i) {
    int dl = i * 32 + (t >> 3), sl = (t & 7) * 8;
    bf16x8 o;
#pragma unroll
    for (int j = 0; j < 8; ++j) o[j] = tile[sl + j][dl];
    *reinterpret_cast<bf16x8*>(Vtb + (size_t)(d0 + dl) * S_LEN + s0 + sl) = o;
  }
}

// flash attention v4: block = (kvh, qt16 via quartet-balanced map); 4 waves =
// 4 heads of the KV group, all same qt (no divergence). 16 q-rows per wave.
// K tile (64x128) in LDS (global_load_lds, double-buffered, src-XOR-swizzled).
// V^T direct from global (L2-resident per XCD). setprio around MFMA clusters.
__global__ __launch_bounds__(256, 4) void attn_kernel(const short* __restrict__ Q,
                                                      const short* __restrict__ Kx,
                                                      const short* __restrict__ Vt,
                                                      short* __restrict__ AO) {
  __shared__ short lK[2 * 64 * 128];   // 32 KiB
  __shared__ short lP[4 * 16 * 72];    // per-wave P[16][64], stride 72
  const int tt = threadIdx.x;
  const int w = tt >> 6, lane = tt & 63;
  const int l15 = lane & 15, l4 = lane >> 4;
  const int kvh = blockIdx.x;
  // quartet balance: CU gets y, y+32, y+64, y+96 -> constant total work
  const int y = blockIdx.y;
  const int a = y & 31, b = y >> 5;
  const int q2 = a * 2 + (b >> 1);
  const int qt = (b & 1) ? (127 - q2) : q2;   // bijective on [0,128)
  const int h = kvh * 4 + w;
  short* P = lP + w * (16 * 72);

  bf16x8 qf[4];
  const short* qrow = Q + ((size_t)h * S_LEN + qt * 16 + l15) * HD + l4 * 8;
#pragma unroll
  for (int fd = 0; fd < 4; ++fd)
    qf[fd] = *reinterpret_cast<const bf16x8*>(qrow + fd * 32);

  f32x4 o[8] = {};
  float m_run[4] = {-1e30f, -1e30f, -1e30f, -1e30f};
  float lsum[4] = {0.f, 0.f, 0.f, 0.f};

  const short* Kb = Kx + (size_t)kvh * S_LEN * HD;
  const short* Vb = Vt + (size_t)kvh * HD * S_LEN;  // [HD][S]
  const int nkt = (qt >> 2) + 1;

  // prologue: stage K tile 0 (source pre-swizzled so linear LDS == swizzled)
#pragma unroll
  for (int i = 0; i < 4; ++i) {
    int c = tt + i * 256, row = c >> 4, jj = (c & 15) ^ (row & 7);
    gl_lds16(Kb + (size_t)row * HD + jj * 8, lK + c * 8);
  }
  __syncthreads();

  int cur = 0;
  for (int kt = 0; kt < nkt; ++kt) {
    const int c0 = kt * 64;
    if (kt + 1 < nkt) {  // prefetch next K tile into other buffer
      const short* Kg = Kb + (size_t)(c0 + 64) * HD;
      short* dst = lK + (cur ^ 1) * (64 * 128);
#pragma unroll
      for (int i = 0; i < 4; ++i) {
        int c = tt + i * 256, row = c >> 4, jj = (c & 15) ^ (row & 7);
        gl_lds16(Kg + (size_t)row * HD + jj * 8, dst + c * 8);
      }
    }
    // QK^T: S[16q][64kv]
    const short* src = lK + cur * (64 * 128);
    f32x4 sf[4] = {};
    __builtin_amdgcn_s_setprio(1);
#pragma unroll
    for (int n = 0; n < 4; ++n) {
      bf16x8 kf[4];
#pragma unroll
      for (int fd = 0; fd < 4; ++fd) {
        int row = n * 16 + l15, jp = (l4 + fd * 4) ^ (l15 & 7);
        kf[fd] = *reinterpret_cast<const bf16x8*>(src + row * 128 + jp * 8);
      }
#pragma unroll
      for (int fd = 0; fd < 4; ++fd)
        sf[n] = __builtin_amdgcn_mfma_f32_16x16x32_bf16(qf[fd], kf[fd], sf[n], 0, 0, 0);
    }
    __builtin_amdgcn_s_setprio(0);
    const bool lastt = (kt == nkt - 1);
#pragma unroll
    for (int n = 0; n < 4; ++n)
#pragma unroll
      for (int r = 0; r < 4; ++r) {
        float v = sf[n][r] * ATT_SCALE;
        if (lastt && (c0 + n * 16 + l15) > (qt * 16 + l4 * 4 + r)) v = -1e30f;
        sf[n][r] = v;
      }
    float alpha[4];
#pragma unroll
    for (int r = 0; r < 4; ++r) {
      float mx = fmaxf(fmaxf(sf[0][r], sf[1][r]), fmaxf(sf[2][r], sf[3][r]));
      mx = fmaxf(mx, __shfl_xor(mx, 1, 64));
      mx = fmaxf(mx, __shfl_xor(mx, 2, 64));
      mx = fmaxf(mx, __shfl_xor(mx, 4, 64));
      mx = fmaxf(mx, __shfl_xor(mx, 8, 64));
      float mnew = fmaxf(m_run[r], mx);
      alpha[r] = __expf(m_run[r] - mnew);
      m_run[r] = mnew;
      float ps = 0.f;
#pragma unroll
      for (int n = 0; n < 4; ++n) {
        float e = __expf(sf[n][r] - mnew);
        sf[n][r] = e;
        ps += e;
      }
      lsum[r] = lsum[r] * alpha[r] + ps;
    }
#pragma unroll
    for (int fd = 0; fd < 8; ++fd) {
      o[fd][0] *= alpha[0]; o[fd][1] *= alpha[1];
      o[fd][2] *= alpha[2]; o[fd][3] *= alpha[3];
    }
    // P -> LDS (A-fragment transpose), per-wave buffer
#pragma unroll
    for (int n = 0; n < 4; ++n)
#pragma unroll
      for (int r = 0; r < 4; ++r)
        P[(l4 * 4 + r) * 72 + n * 16 + l15] = f2bf(sf[n][r]);
    asm volatile("s_waitcnt lgkmcnt(0)" ::: "memory");
    bf16x8 pf0 = *reinterpret_cast<const bf16x8*>(P + l15 * 72 + l4 * 8);
    bf16x8 pf1 = *reinterpret_cast<const bf16x8*>(P + l15 * 72 + 32 + l4 * 8);
    // PV: O[16q][128d] += P[16q][64kv] * V[64kv][128d]
    __builtin_amdgcn_s_setprio(1);
#pragma unroll
    for (int fd = 0; fd < 8; ++fd) {
      const short* vrow = Vb + (size_t)(fd * 16 + l15) * S_LEN + c0 + l4 * 8;
      bf16x8 vf0 = *reinterpret_cast<const bf16x8*>(vrow);
      bf16x8 vf1 = *reinterpret_cast<const bf16x8*>(vrow + 32);
      o[fd] = __builtin_amdgcn_mfma_f32_16x16x32_bf16(pf0, vf0, o[fd], 0, 0, 0);
      o[fd] = __builtin_amdgcn_mfma_f32_16x16x32_bf16(pf1, vf1, o[fd], 0, 0, 0);
    }
    __builtin_amdgcn_s_setprio(0);
    __syncthreads();  // drains vmcnt(0): prefetched K landed; LDS reuse safe
    cur ^= 1;
  }
  float inv[4];
#pragma unroll
  for (int r = 0; r < 4; ++r) {
    float s = lsum[r];
    s += __shfl_xor(s, 1, 64);
    s += __shfl_xor(s, 2, 64);
    s += __shfl_xor(s, 4, 64);
    s += __shfl_xor(s, 8, 64);
    inv[r] = 1.f / s;
  }
#pragma unroll
  for (int fd = 0; fd < 8; ++fd)
#pragma unroll
    for (int r = 0; r < 4; ++r)
      AO[(size_t)(qt * 16 + l4 * 4 + r) * HDIM + h * HD + fd * 16 + l15] =
          f2bf(o[fd][r] * inv[r]);
}

extern "C" void kernel_launch(void* const* d_in, const int* in_sizes, int n_in,
                              void* d_out, int out_size, void* d_ws, size_t ws_size,
                              hipStream_t stream) {
  const float* hidden = (const float*)d_in[0];
  const float* w_attn = (const float*)d_in[1];
  const float* w_proj = (const float*)d_in[2];
  const float* rcos = (const float*)d_in[3];
  const float* rsin = (const float*)d_in[4];
  float* out = (float*)d_out;
  char* ws = (char*)d_ws;

  // workspace layout (112 MiB total, overlaid):
  //  [0,16Mi)    Xb (bf16 X)          -> reused as AO after gemm1
  //  [16,64Mi)   Wab (bf16 w_attn)    -> after gemm1: Qb[16,32) Kb[32,36) Vb[36,40) Vtb[40,44)
  //  [64,112Mi)  QKVf (fp32 qkv)      -> reused as Wpb (bf16 w_proj) after rope
  short* Xb  = (short*)(ws);
  short* Wab = (short*)(ws + (16u << 20));
  short* Qb  = (short*)(ws + (16u << 20));
  short* Kb  = (short*)(ws + (32u << 20));
  short* Vb  = (short*)(ws + (36u << 20));
  short* Vtb = (short*)(ws + (40u << 20));
  float* QKVf = (float*)(ws + (64u << 20));
  short* Wpb = (short*)(ws + (64u << 20));
  short* AO  = Xb;

  const int nX = S_LEN * HDIM;
  const int nWa = QKVD * HDIM;
  const int nWp = HDIM * HDIM;

  cvt_kernel<<<nX / 1024, 256, 0, stream>>>(hidden, Xb, nX);
  cvt_kernel<<<nWa / 1024, 256, 0, stream>>>(w_attn, Wab, nWa);
  gemm_lds<<<dim3(QKVD / 128, S_LEN / 128), 256, 0, stream>>>(Xb, Wab, QKVf, S_LEN, QKVD, HDIM);
  rope_kernel<<<(S_LEN * QKVD) / 256, 256, 0, stream>>>(QKVf, rcos, rsin, Qb, Kb, Vb);
  vtrans_kernel<<<dim3(S_LEN / 64, HD / 64, NKVH), 256, 0, stream>>>(Vb, Vtb);
  cvt_kernel<<<nWp / 1024, 256, 0, stream>>>(w_proj, Wpb, nWp);
  attn_kernel<<<dim3(NKVH, 128), 256, 0, stream>>>(Qb, Kb, Vtb, AO);
  gemm_lds<<<dim3(HDIM / 128, S_LEN / 128), 256, 0, stream>>>(AO, Wpb, out, S_LEN, HDIM, HDIM);
}

// Round 5
// 434.978 us; speedup vs baseline: 1.2585x; 1.2585x over previous
//
#include <hip/hip_runtime.h>
#include <cstdint>
#include <cstddef>

typedef __attribute__((ext_vector_type(4))) float f32x4;
typedef __attribute__((ext_vector_type(8))) short bf16x8;

#define S_LEN 2048
#define HDIM 4096
#define QKVD 6144
#define NHEAD 32
#define NKVH 8
#define HD 128
#define ATT_SCALE 0.08838834764831845f

// fp32 -> bf16 RNE (finite inputs only)
__device__ __forceinline__ short f2bf(float f) {
  unsigned int u = __float_as_uint(f);
  u += 0x7FFFu + ((u >> 16) & 1u);
  return (short)(u >> 16);
}

// async global->LDS, 16B per lane. LDS dest = wave-uniform base + lane*16.
__device__ __forceinline__ void gl_lds16(const short* g, short* l) {
  __builtin_amdgcn_global_load_lds((const __attribute__((address_space(1))) void*)g,
                                   (__attribute__((address_space(3))) void*)l,
                                   16, 0, 0);
}

__global__ void cvt_kernel(const float* __restrict__ in, short* __restrict__ out, int n) {
  int i = (blockIdx.x * blockDim.x + threadIdx.x) * 4;
  if (i >= n) return;
  const float4 v = *reinterpret_cast<const float4*>(in + i);
  short4 o;
  o.x = f2bf(v.x); o.y = f2bf(v.y); o.z = f2bf(v.z); o.w = f2bf(v.w);
  *reinterpret_cast<short4*>(out + i) = o;
}

// C[M][N] = A[M][K] * B[N][K]^T (bf16 in, fp32 out), 128x128 tile, BK=32,
// m97 structure: global_load_lds width=16, 2 barriers per K-step.
__global__ __launch_bounds__(256) void gemm_lds(const short* __restrict__ A,
                                                const short* __restrict__ B,
                                                float* __restrict__ C,
                                                int M, int N, int K) {
  __shared__ short lA[128 * 32];
  __shared__ short lB[128 * 32];
  const int t = threadIdx.x;
  const int w = t >> 6, lane = t & 63;
  const int l15 = lane & 15, l4 = lane >> 4;
  const int tm = blockIdx.y * 128, tn = blockIdx.x * 128;
  const int wr = (w >> 1) * 64, wc = (w & 1) * 64;

  const int c0 = w * 128 + lane, c1 = c0 + 64;
  const short* gA0 = A + (size_t)(tm + (c0 >> 2)) * K + (c0 & 3) * 8;
  const short* gA1 = A + (size_t)(tm + (c1 >> 2)) * K + (c1 & 3) * 8;
  const short* gB0 = B + (size_t)(tn + (c0 >> 2)) * K + (c0 & 3) * 8;
  const short* gB1 = B + (size_t)(tn + (c1 >> 2)) * K + (c1 & 3) * 8;
  short* lA0 = lA + c0 * 8; short* lA1 = lA + c1 * 8;
  short* lB0 = lB + c0 * 8; short* lB1 = lB + c1 * 8;

  f32x4 acc[4][4] = {};

  for (int k0 = 0; k0 < K; k0 += 32) {
    gl_lds16(gA0 + k0, lA0);
    gl_lds16(gA1 + k0, lA1);
    gl_lds16(gB0 + k0, lB0);
    gl_lds16(gB1 + k0, lB1);
    __syncthreads();
    bf16x8 af[4], bfr[4];
#pragma unroll
    for (int m = 0; m < 4; ++m)
      af[m] = *reinterpret_cast<const bf16x8*>(lA + (wr + m * 16 + l15) * 32 + l4 * 8);
#pragma unroll
    for (int n = 0; n < 4; ++n)
      bfr[n] = *reinterpret_cast<const bf16x8*>(lB + (wc + n * 16 + l15) * 32 + l4 * 8);
#pragma unroll
    for (int m = 0; m < 4; ++m)
#pragma unroll
      for (int n = 0; n < 4; ++n)
        acc[m][n] = __builtin_amdgcn_mfma_f32_16x16x32_bf16(af[m], bfr[n], acc[m][n], 0, 0, 0);
    __syncthreads();
  }
#pragma unroll
  for (int m = 0; m < 4; ++m)
#pragma unroll
    for (int n = 0; n < 4; ++n)
#pragma unroll
      for (int r = 0; r < 4; ++r) {
        int rr = tm + wr + m * 16 + l4 * 4 + r;
        int cc = tn + wc + n * 16 + l15;
        C[(size_t)rr * N + cc] = acc[m][n][r];
      }
}

// qkv fp32 [S][6144] -> roped bf16 Q[NH][S][HD], K[NKV][S][HD], V[NKV][S][HD]
__global__ void rope_kernel(const float* __restrict__ qkv,
                            const float* __restrict__ cb,
                            const float* __restrict__ sb,
                            short* __restrict__ Q,
                            short* __restrict__ Kx,
                            short* __restrict__ V) {
  int tid = blockIdx.x * blockDim.x + threadIdx.x;
  int s = tid / QKVD;
  int j = tid - s * QKVD;
  int g = j / 768;
  int idx = j - g * 768;
  float val = qkv[tid];
  if (idx < 640) {
    int part = idx >> 7;  // 0..3 = q heads in group, 4 = k
    int d = idx & 127;
    int d2 = (d < 64) ? d + 64 : d - 64;
    float pv = qkv[(size_t)s * QKVD + g * 768 + part * 128 + d2];
    float c = cb[s * HD + d], sn = sb[s * HD + d];
    float ov = (d < 64) ? (val * c - pv * sn) : (val * c + pv * sn);
    if (part < 4) {
      int hh = g * 4 + part;
      Q[((size_t)hh * S_LEN + s) * HD + d] = f2bf(ov);
    } else {
      Kx[((size_t)g * S_LEN + s) * HD + d] = f2bf(ov);
    }
  } else {
    int d = idx - 640;
    V[((size_t)g * S_LEN + s) * HD + d] = f2bf(val);
  }
}

// V [NKVH][S][HD] -> Vt [NKVH][HD][S], 64x64 LDS tiles, coalesced both sides
__global__ __launch_bounds__(256) void vtrans_kernel(const short* __restrict__ V,
                                                     short* __restrict__ Vt) {
  __shared__ short tile[64][72];
  const int kvh = blockIdx.z;
  const int s0 = blockIdx.x * 64, d0 = blockIdx.y * 64;
  const int t = threadIdx.x;
  const short* Vb = V + (size_t)kvh * S_LEN * HD;
  short* Vtb = Vt + (size_t)kvh * HD * S_LEN;
#pragma unroll
  for (int i = 0; i < 2; ++i) {
    int sl = i * 32 + (t >> 3), dl = (t & 7) * 8;
    bf16x8 v = *reinterpret_cast<const bf16x8*>(Vb + (size_t)(s0 + sl) * HD + d0 + dl);
    *reinterpret_cast<bf16x8*>(&tile[sl][dl]) = v;
  }
  __syncthreads();
#pragma unroll
  for (int i = 0; i < 2; ++i) {
    int dl = i * 32 + (t >> 3), sl = (t & 7) * 8;
    bf16x8 o;
#pragma unroll
    for (int j = 0; j < 8; ++j) o[j] = tile[sl + j][dl];
    *reinterpret_cast<bf16x8*>(Vtb + (size_t)(d0 + dl) * S_LEN + s0 + sl) = o;
  }
}

// flash attention v5: 4 waves = 4 heads of one KV group; 32 q-rows per wave.
// SWAPPED QK^T (mfma(K,Q)) -> per-lane row softmax (2 shfl only); P written
// directly in A-fragment order (zero-conflict b128 reads); V-loads issued
// before softmax (latency hidden); K LDS double-buffered via global_load_lds.
// Pair-balanced qt map: CU gets (y, y+32) -> constant work.
__global__ __launch_bounds__(256, 2) void attn_kernel(const short* __restrict__ Q,
                                                      const short* __restrict__ Kx,
                                                      const short* __restrict__ Vt,
                                                      short* __restrict__ AO) {
  __shared__ short lK[2 * 64 * 128];   // 32 KiB, XOR-swizzled (source-side)
  __shared__ unsigned int lPu[4 * 2 * 512];  // 16 KiB: per-wave, per-qa P in A-frag order
  const int tt = threadIdx.x;
  const int w = tt >> 6, lane = tt & 63;
  const int l15 = lane & 15, l4 = lane >> 4;
  const int kvh = blockIdx.x;
  const int y = blockIdx.y;
  const int qt = (y < 32) ? (2 * y) : (127 - 2 * y);  // pair-balance: (y,y+32) -> 33 tiles
  const int h = kvh * 4 + w;

  bf16x8 qf[2][4];
#pragma unroll
  for (int qa = 0; qa < 2; ++qa) {
    const short* qrow = Q + ((size_t)h * S_LEN + qt * 32 + qa * 16 + l15) * HD + l4 * 8;
#pragma unroll
    for (int fd = 0; fd < 4; ++fd)
      qf[qa][fd] = *reinterpret_cast<const bf16x8*>(qrow + fd * 32);
  }

  f32x4 o[2][8] = {};
  float m_run[2] = {-1e30f, -1e30f};
  float lsum[2] = {0.f, 0.f};

  const short* Kb = Kx + (size_t)kvh * S_LEN * HD;
  const short* Vb = Vt + (size_t)kvh * HD * S_LEN;  // [HD][S]
  const int nkt = (qt >> 1) + 1;

  // prologue: stage K tile 0 (source pre-swizzled so linear LDS == swizzled)
#pragma unroll
  for (int i = 0; i < 4; ++i) {
    int c = tt + i * 256, row = c >> 4, jj = (c & 15) ^ (row & 7);
    gl_lds16(Kb + (size_t)row * HD + jj * 8, lK + c * 8);
  }
  __syncthreads();

  int cur = 0;
  for (int kt = 0; kt < nkt; ++kt) {
    const int c0 = kt * 64;
    if (kt + 1 < nkt) {  // prefetch next K tile into other buffer
      const short* Kg = Kb + (size_t)(c0 + 64) * HD;
      short* dst = lK + (cur ^ 1) * (64 * 128);
#pragma unroll
      for (int i = 0; i < 4; ++i) {
        int c = tt + i * 256, row = c >> 4, jj = (c & 15) ^ (row & 7);
        gl_lds16(Kg + (size_t)row * HD + jj * 8, dst + c * 8);
      }
    }
    // QK^T swapped: S^T[64kv][32q]; lane holds row q=l15(+qa*16), kv=n*16+l4*4+r
    const short* src = lK + cur * (64 * 128);
    f32x4 sf[2][4] = {};
    __builtin_amdgcn_s_setprio(1);
#pragma unroll
    for (int n = 0; n < 4; ++n) {
      bf16x8 kf[4];
#pragma unroll
      for (int fd = 0; fd < 4; ++fd) {
        int row = n * 16 + l15, jp = (l4 + fd * 4) ^ (l15 & 7);
        kf[fd] = *reinterpret_cast<const bf16x8*>(src + row * 128 + jp * 8);
      }
#pragma unroll
      for (int fd = 0; fd < 4; ++fd) {
        sf[0][n] = __builtin_amdgcn_mfma_f32_16x16x32_bf16(kf[fd], qf[0][fd], sf[0][n], 0, 0, 0);
        sf[1][n] = __builtin_amdgcn_mfma_f32_16x16x32_bf16(kf[fd], qf[1][fd], sf[1][n], 0, 0, 0);
      }
    }
    __builtin_amdgcn_s_setprio(0);
    // issue V loads early: latency hides under softmax
    bf16x8 vreg[8][2];
#pragma unroll
    for (int fd = 0; fd < 8; ++fd) {
      const short* vrow = Vb + (size_t)(fd * 16 + l15) * S_LEN + c0 + l4 * 8;
      vreg[fd][0] = *reinterpret_cast<const bf16x8*>(vrow);
      vreg[fd][1] = *reinterpret_cast<const bf16x8*>(vrow + 32);
    }
    const bool lastt = (kt == nkt - 1);
#pragma unroll
    for (int qa = 0; qa < 2; ++qa) {
      const int qrow_g = qt * 32 + qa * 16 + l15;
#pragma unroll
      for (int n = 0; n < 4; ++n)
#pragma unroll
        for (int r = 0; r < 4; ++r) {
          float v = sf[qa][n][r] * ATT_SCALE;
          if (lastt && (c0 + n * 16 + l4 * 4 + r) > qrow_g) v = -1e30f;
          sf[qa][n][r] = v;
        }
      // row max: 15 in-register fmax + 2 shfl (across l4 groups)
      float mx = sf[qa][0][0];
#pragma unroll
      for (int n = 0; n < 4; ++n)
#pragma unroll
        for (int r = 0; r < 4; ++r) mx = fmaxf(mx, sf[qa][n][r]);
      mx = fmaxf(mx, __shfl_xor(mx, 16, 64));
      mx = fmaxf(mx, __shfl_xor(mx, 32, 64));
      float mnew = fmaxf(m_run[qa], mx);
      float alpha = __expf(m_run[qa] - mnew);
      m_run[qa] = mnew;
      float ps = 0.f;
#pragma unroll
      for (int n = 0; n < 4; ++n)
#pragma unroll
        for (int r = 0; r < 4; ++r) {
          float e = __expf(sf[qa][n][r] - mnew);
          sf[qa][n][r] = e;
          ps += e;
        }
      lsum[qa] = lsum[qa] * alpha + ps;
      // pack pairs, write straight into A-fragment order (read = lane-linear)
#pragma unroll
      for (int n = 0; n < 4; ++n)
#pragma unroll
        for (int rp = 0; rp < 2; ++rp) {
          unsigned int pkv =
              ((unsigned int)(unsigned short)f2bf(sf[qa][n][rp * 2 + 1]) << 16) |
              (unsigned short)f2bf(sf[qa][n][rp * 2]);
          int kv5 = ((n & 1) << 4) + l4 * 4 + rp * 2;
          lPu[w * 1024 + qa * 512 + ((n >> 1) << 8) +
              (l15 + ((kv5 >> 3) << 4)) * 4 + ((kv5 & 7) >> 1)] = pkv;
        }
      // alpha -> O domain (q = l4*4+r), rescale accumulator
      float aO[4];
#pragma unroll
      for (int r = 0; r < 4; ++r) aO[r] = __shfl(alpha, l4 * 4 + r, 64);
#pragma unroll
      for (int fd = 0; fd < 8; ++fd) {
        o[qa][fd][0] *= aO[0]; o[qa][fd][1] *= aO[1];
        o[qa][fd][2] *= aO[2]; o[qa][fd][3] *= aO[3];
      }
    }
    asm volatile("s_waitcnt lgkmcnt(0)" ::: "memory");
    bf16x8 pf[2][2];
#pragma unroll
    for (int qa = 0; qa < 2; ++qa)
#pragma unroll
      for (int p = 0; p < 2; ++p)
        pf[qa][p] = *reinterpret_cast<const bf16x8*>(
            (const short*)lPu + (w * 1024 + qa * 512 + p * 256 + lane * 4) * 2);
    // PV: O[32q][128d] += P[32q][64kv] * V[64kv][128d]
    __builtin_amdgcn_s_setprio(1);
#pragma unroll
    for (int fd = 0; fd < 8; ++fd) {
      o[0][fd] = __builtin_amdgcn_mfma_f32_16x16x32_bf16(pf[0][0], vreg[fd][0], o[0][fd], 0, 0, 0);
      o[0][fd] = __builtin_amdgcn_mfma_f32_16x16x32_bf16(pf[0][1], vreg[fd][1], o[0][fd], 0, 0, 0);
      o[1][fd] = __builtin_amdgcn_mfma_f32_16x16x32_bf16(pf[1][0], vreg[fd][0], o[1][fd], 0, 0, 0);
      o[1][fd] = __builtin_amdgcn_mfma_f32_16x16x32_bf16(pf[1][1], vreg[fd][1], o[1][fd], 0, 0, 0);
    }
    __builtin_amdgcn_s_setprio(0);
    __syncthreads();  // drains vmcnt(0): prefetched K landed; lP reuse safe
    cur ^= 1;
  }
#pragma unroll
  for (int qa = 0; qa < 2; ++qa) {
    float s = lsum[qa];
    s += __shfl_xor(s, 16, 64);
    s += __shfl_xor(s, 32, 64);
    float inv = 1.f / s;
    float iO[4];
#pragma unroll
    for (int r = 0; r < 4; ++r) iO[r] = __shfl(inv, l4 * 4 + r, 64);
#pragma unroll
    for (int fd = 0; fd < 8; ++fd)
#pragma unroll
      for (int r = 0; r < 4; ++r)
        AO[(size_t)(qt * 32 + qa * 16 + l4 * 4 + r) * HDIM + h * HD + fd * 16 + l15] =
            f2bf(o[qa][fd][r] * iO[r]);
  }
}

extern "C" void kernel_launch(void* const* d_in, const int* in_sizes, int n_in,
                              void* d_out, int out_size, void* d_ws, size_t ws_size,
                              hipStream_t stream) {
  const float* hidden = (const float*)d_in[0];
  const float* w_attn = (const float*)d_in[1];
  const float* w_proj = (const float*)d_in[2];
  const float* rcos = (const float*)d_in[3];
  const float* rsin = (const float*)d_in[4];
  float* out = (float*)d_out;
  char* ws = (char*)d_ws;

  // workspace layout (112 MiB total, overlaid):
  //  [0,16Mi)    Xb (bf16 X)          -> reused as AO after gemm1
  //  [16,64Mi)   Wab (bf16 w_attn)    -> after gemm1: Qb[16,32) Kb[32,36) Vb[36,40) Vtb[40,44)
  //  [64,112Mi)  QKVf (fp32 qkv)      -> reused as Wpb (bf16 w_proj) after rope
  short* Xb  = (short*)(ws);
  short* Wab = (short*)(ws + (16u << 20));
  short* Qb  = (short*)(ws + (16u << 20));
  short* Kb  = (short*)(ws + (32u << 20));
  short* Vb  = (short*)(ws + (36u << 20));
  short* Vtb = (short*)(ws + (40u << 20));
  float* QKVf = (float*)(ws + (64u << 20));
  short* Wpb = (short*)(ws + (64u << 20));
  short* AO  = Xb;

  const int nX = S_LEN * HDIM;
  const int nWa = QKVD * HDIM;
  const int nWp = HDIM * HDIM;

  cvt_kernel<<<nX / 1024, 256, 0, stream>>>(hidden, Xb, nX);
  cvt_kernel<<<nWa / 1024, 256, 0, stream>>>(w_attn, Wab, nWa);
  gemm_lds<<<dim3(QKVD / 128, S_LEN / 128), 256, 0, stream>>>(Xb, Wab, QKVf, S_LEN, QKVD, HDIM);
  rope_kernel<<<(S_LEN * QKVD) / 256, 256, 0, stream>>>(QKVf, rcos, rsin, Qb, Kb, Vb);
  vtrans_kernel<<<dim3(S_LEN / 64, HD / 64, NKVH), 256, 0, stream>>>(Vb, Vtb);
  cvt_kernel<<<nWp / 1024, 256, 0, stream>>>(w_proj, Wpb, nWp);
  attn_kernel<<<dim3(NKVH, 64), 256, 0, stream>>>(Qb, Kb, Vtb, AO);
  gemm_lds<<<dim3(HDIM / 128, S_LEN / 128), 256, 0, stream>>>(AO, Wpb, out, S_LEN, HDIM, HDIM);
}

// Round 7
// 366.542 us; speedup vs baseline: 1.4935x; 1.1867x over previous
//
#include <hip/hip_runtime.h>
#include <cstdint>
#include <cstddef>

typedef __attribute__((ext_vector_type(4))) float f32x4;
typedef __attribute__((ext_vector_type(8))) short bf16x8;

#define S_LEN 2048
#define HDIM 4096
#define QKVD 6144
#define NHEAD 32
#define NKVH 8
#define HD 128
#define ATT_SCALE 0.08838834764831845f

// fp32 -> bf16 RNE (finite inputs only)
__device__ __forceinline__ short f2bf(float f) {
  unsigned int u = __float_as_uint(f);
  u += 0x7FFFu + ((u >> 16) & 1u);
  return (short)(u >> 16);
}

// async global->LDS, 16B per lane. LDS dest = wave-uniform base + lane*16.
__device__ __forceinline__ void gl_lds16(const short* g, short* l) {
  __builtin_amdgcn_global_load_lds((const __attribute__((address_space(1))) void*)g,
                                   (__attribute__((address_space(3))) void*)l,
                                   16, 0, 0);
}

template<int N> __device__ __forceinline__ void vmw() {
  if constexpr (N == 0) asm volatile("s_waitcnt vmcnt(0)" ::: "memory");
  else if constexpr (N == 1) asm volatile("s_waitcnt vmcnt(1)" ::: "memory");
  else if constexpr (N == 2) asm volatile("s_waitcnt vmcnt(2)" ::: "memory");
  else if constexpr (N == 3) asm volatile("s_waitcnt vmcnt(3)" ::: "memory");
  else if constexpr (N == 4) asm volatile("s_waitcnt vmcnt(4)" ::: "memory");
  // N==99: no wait
}

__global__ void cvt_kernel(const float* __restrict__ in, short* __restrict__ out, int n) {
  int i = (blockIdx.x * blockDim.x + threadIdx.x) * 4;
  if (i >= n) return;
  const float4 v = *reinterpret_cast<const float4*>(in + i);
  short4 o;
  o.x = f2bf(v.x); o.y = f2bf(v.y); o.z = f2bf(v.z); o.w = f2bf(v.w);
  *reinterpret_cast<short4*>(out + i) = o;
}

// ---------------------------------------------------------------------------
// 4-phase-per-K-tile deep-pipelined GEMM: C = A[M][K] * B[N][K]^T, bf16->fp32.
// BM x 256 tile, BK=64, 512 threads (8 waves, 2M x 4N), LDS double-buffered.
// Phase = { ds_read quadrant frags (region guaranteed by prior vmcnt+barrier)
//           -> issue ONE stage unit of tile t+1 -> vmcnt(counted) -> s_barrier
//           -> setprio(1) 16 MFMA setprio(0) }.
// Region->needed-by: A_lo,B_ev @ phase0; B_od @ phase1; A_hi @ phase2.
// A region R is only ds_read after {every wave's vmcnt covering R} + barrier,
// which closes the cross-wave RAW race (vmcnt is per-wave!). Stage units write
// the opposite LDS buffer, and a buffer is reused >=3 barriers after its last
// read -> no WAR.
// ---------------------------------------------------------------------------
#define PHASEX(MH, NH, VM, STAGE) { \
    bf16x8 af[MQ][2], bfr[2][2]; \
    { const short* bA = lA + buf * ATILE; const short* bB = lB + buf * BTILE; \
      _Pragma("unroll") for (int m = 0; m < MQ; ++m) { \
        int row = wm * (BM >> 1) + (MH) * (BM >> 2) + m * 16 + l15; \
        _Pragma("unroll") for (int kk = 0; kk < 2; ++kk) { \
          int slot = ((kk << 2) + l4) ^ (row & 7); \
          af[m][kk] = *reinterpret_cast<const bf16x8*>(bA + row * 64 + slot * 8); } } \
      _Pragma("unroll") for (int n = 0; n < 2; ++n) { \
        int row = wn * 64 + (NH) * 32 + n * 16 + l15; \
        _Pragma("unroll") for (int kk = 0; kk < 2; ++kk) { \
          int slot = ((kk << 2) + l4) ^ (row & 7); \
          bfr[n][kk] = *reinterpret_cast<const bf16x8*>(bB + row * 64 + slot * 8); } } } \
    STAGE; \
    vmw<(VM)>(); \
    __builtin_amdgcn_s_barrier(); \
    __builtin_amdgcn_sched_barrier(0); \
    __builtin_amdgcn_s_setprio(1); \
    _Pragma("unroll") for (int m = 0; m < MQ; ++m) \
      _Pragma("unroll") for (int n = 0; n < 2; ++n) \
        _Pragma("unroll") for (int kk = 0; kk < 2; ++kk) \
          acc[(MH) * MQ + m][(NH) * 2 + n] = __builtin_amdgcn_mfma_f32_16x16x32_bf16( \
              af[m][kk], bfr[n][kk], acc[(MH) * MQ + m][(NH) * 2 + n], 0, 0, 0); \
    __builtin_amdgcn_s_setprio(0); }

template<int BM>
__global__ __launch_bounds__(512, 2) void gemm8p(const short* __restrict__ A,
                                                 const short* __restrict__ B,
                                                 float* __restrict__ C,
                                                 int M, int N, int K) {
  extern __shared__ short sm[];
  constexpr int MQ = BM / 64;     // A-frags per quadrant phase
  constexpr int MR = BM / 32;     // total M fragments per wave
  constexpr int ATILE = BM * 64;  // shorts per A tile buffer
  constexpr int BTILE = 256 * 64;
  const int tid = threadIdx.x;
  const int wv = tid >> 6, lane = tid & 63;
  const int wm = wv >> 2, wn = wv & 3;  // 2 x 4 wave grid
  const int l15 = lane & 15, l4 = lane >> 4;
  const int nbn = N >> 8;
  const int nwg = gridDim.x;
  const int bid = blockIdx.x;
  const int sbid = (bid & 7) * (nwg >> 3) + (bid >> 3);  // XCD-contiguous (nwg%8==0)
  const int tm = (sbid / nbn) * BM, tn = (sbid % nbn) * 256;
  short* lA = sm;                  // [2][BM][64], st-swizzled
  short* lB = sm + 2 * ATILE;      // [2][256][64], st-swizzled
  (void)M;

  f32x4 acc[MR][4] = {};

  // unit S_0/S_3: A sel=0 -> rows [0,BM/4)+[BM/2,3BM/4); sel=1 -> high quarters
  auto stageA = [&](int k0, int bufi, int sel) {
    short* dst = lA + bufi * ATILE;
#pragma unroll
    for (int j = 0; j < (BM == 256 ? 2 : 1); ++j) {
      int c = tid + j * 512;
      int blk = (BM == 256) ? (c >> 9) : (c >> 8);
      int rowoff = (BM == 256) ? ((c >> 3) & 63) : ((c >> 3) & 31);
      int slot = c & 7;
      int row = blk * (BM >> 1) + sel * (BM >> 2) + rowoff;
      gl_lds16(A + (size_t)(tm + row) * K + k0 + ((slot ^ (row & 7)) << 3),
               dst + row * 64 + slot * 8);
    }
  };
  // unit S_1/S_2: B par=0 -> rows wn*64+[0,32) all wn; par=1 -> wn*64+[32,64)
  auto stageB = [&](int k0, int bufi, int par) {
    short* dst = lB + bufi * BTILE;
#pragma unroll
    for (int j = 0; j < 2; ++j) {
      int c = tid + j * 512;
      int blk = c >> 8;
      int rowoff = (c >> 3) & 31;
      int slot = c & 7;
      int row = blk * 64 + par * 32 + rowoff;
      gl_lds16(B + (size_t)(tn + row) * K + k0 + ((slot ^ (row & 7)) << 3),
               dst + row * 64 + slot * 8);
    }
  };

  // prologue: tile 0, issue order = consume order; then guarantee S_0,S_1
  stageA(0, 0, 0);  // S_0: A-low
  stageB(0, 0, 0);  // S_1: B-even
  stageB(0, 0, 1);  // S_2: B-odd
  stageA(0, 0, 1);  // S_3: A-high
  vmw<(BM == 256 ? 4 : 3)>();
  __builtin_amdgcn_s_barrier();
  __builtin_amdgcn_sched_barrier(0);

  const int KT = K >> 6;
  for (int t = 0; t < KT - 1; ++t) {
    const int buf = t & 1, nbuf = buf ^ 1, nk0 = (t + 1) << 6;
    PHASEX(0, 0, (BM == 256 ? 4 : 2), stageA(nk0, nbuf, 0))
    PHASEX(0, 1, (BM == 256 ? 4 : 3), stageB(nk0, nbuf, 0))
    PHASEX(1, 0, 99,                  stageB(nk0, nbuf, 1))
    PHASEX(1, 1, (BM == 256 ? 4 : 3), stageA(nk0, nbuf, 1))
  }
  {  // tail tile: no staging; drain progressively
    const int buf = (KT - 1) & 1;
    PHASEX(0, 0, (BM == 256 ? 2 : 1), (void)0)
    PHASEX(0, 1, 0,                   (void)0)
    PHASEX(1, 0, 99,                  (void)0)
    PHASEX(1, 1, 99,                  (void)0)
  }
#pragma unroll
  for (int m = 0; m < MR; ++m)
#pragma unroll
    for (int n = 0; n < 4; ++n)
#pragma unroll
      for (int r = 0; r < 4; ++r) {
        int row = tm + wm * (BM >> 1) + m * 16 + l4 * 4 + r;
        int col = tn + wn * 64 + n * 16 + l15;
        C[(size_t)row * N + col] = acc[m][n][r];
      }
}

// qkv fp32 [S][6144] -> roped bf16 Q[NH][S][HD], K[NKV][S][HD], V[NKV][S][HD]
__global__ void rope_kernel(const float* __restrict__ qkv,
                            const float* __restrict__ cb,
                            const float* __restrict__ sb,
                            short* __restrict__ Q,
                            short* __restrict__ Kx,
                            short* __restrict__ V) {
  int tid = blockIdx.x * blockDim.x + threadIdx.x;
  int s = tid / QKVD;
  int j = tid - s * QKVD;
  int g = j / 768;
  int idx = j - g * 768;
  float val = qkv[tid];
  if (idx < 640) {
    int part = idx >> 7;  // 0..3 = q heads in group, 4 = k
    int d = idx & 127;
    int d2 = (d < 64) ? d + 64 : d - 64;
    float pv = qkv[(size_t)s * QKVD + g * 768 + part * 128 + d2];
    float c = cb[s * HD + d], sn = sb[s * HD + d];
    float ov = (d < 64) ? (val * c - pv * sn) : (val * c + pv * sn);
    if (part < 4) {
      int hh = g * 4 + part;
      Q[((size_t)hh * S_LEN + s) * HD + d] = f2bf(ov);
    } else {
      Kx[((size_t)g * S_LEN + s) * HD + d] = f2bf(ov);
    }
  } else {
    int d = idx - 640;
    V[((size_t)g * S_LEN + s) * HD + d] = f2bf(val);
  }
}

// V [NKVH][S][HD] -> Vt [NKVH][HD][S], 64x64 LDS tiles, coalesced both sides
__global__ __launch_bounds__(256) void vtrans_kernel(const short* __restrict__ V,
                                                     short* __restrict__ Vt) {
  __shared__ short tile[64][72];
  const int kvh = blockIdx.z;
  const int s0 = blockIdx.x * 64, d0 = blockIdx.y * 64;
  const int t = threadIdx.x;
  const short* Vb = V + (size_t)kvh * S_LEN * HD;
  short* Vtb = Vt + (size_t)kvh * HD * S_LEN;
#pragma unroll
  for (int i = 0; i < 2; ++i) {
    int sl = i * 32 + (t >> 3), dl = (t & 7) * 8;
    bf16x8 v = *reinterpret_cast<const bf16x8*>(Vb + (size_t)(s0 + sl) * HD + d0 + dl);
    *reinterpret_cast<bf16x8*>(&tile[sl][dl]) = v;
  }
  __syncthreads();
#pragma unroll
  for (int i = 0; i < 2; ++i) {
    int dl = i * 32 + (t >> 3), sl = (t & 7) * 8;
    bf16x8 o;
#pragma unroll
    for (int j = 0; j < 8; ++j) o[j] = tile[sl + j][dl];
    *reinterpret_cast<bf16x8*>(Vtb + (size_t)(d0 + dl) * S_LEN + s0 + sl) = o;
  }
}

// flash attention v5 (unchanged from round 5, passing)
__global__ __launch_bounds__(256, 2) void attn_kernel(const short* __restrict__ Q,
                                                      const short* __restrict__ Kx,
                                                      const short* __restrict__ Vt,
                                                      short* __restrict__ AO) {
  __shared__ short lK[2 * 64 * 128];
  __shared__ unsigned int lPu[4 * 2 * 512];
  const int tt = threadIdx.x;
  const int w = tt >> 6, lane = tt & 63;
  const int l15 = lane & 15, l4 = lane >> 4;
  const int kvh = blockIdx.x;
  const int y = blockIdx.y;
  const int qt = (y < 32) ? (2 * y) : (127 - 2 * y);
  const int h = kvh * 4 + w;

  bf16x8 qf[2][4];
#pragma unroll
  for (int qa = 0; qa < 2; ++qa) {
    const short* qrow = Q + ((size_t)h * S_LEN + qt * 32 + qa * 16 + l15) * HD + l4 * 8;
#pragma unroll
    for (int fd = 0; fd < 4; ++fd)
      qf[qa][fd] = *reinterpret_cast<const bf16x8*>(qrow + fd * 32);
  }

  f32x4 o[2][8] = {};
  float m_run[2] = {-1e30f, -1e30f};
  float lsum[2] = {0.f, 0.f};

  const short* Kb = Kx + (size_t)kvh * S_LEN * HD;
  const short* Vb = Vt + (size_t)kvh * HD * S_LEN;
  const int nkt = (qt >> 1) + 1;

#pragma unroll
  for (int i = 0; i < 4; ++i) {
    int c = tt + i * 256, row = c >> 4, jj = (c & 15) ^ (row & 7);
    gl_lds16(Kb + (size_t)row * HD + jj * 8, lK + c * 8);
  }
  __syncthreads();

  int cur = 0;
  for (int kt = 0; kt < nkt; ++kt) {
    const int c0 = kt * 64;
    if (kt + 1 < nkt) {
      const short* Kg = Kb + (size_t)(c0 + 64) * HD;
      short* dst = lK + (cur ^ 1) * (64 * 128);
#pragma unroll
      for (int i = 0; i < 4; ++i) {
        int c = tt + i * 256, row = c >> 4, jj = (c & 15) ^ (row & 7);
        gl_lds16(Kg + (size_t)row * HD + jj * 8, dst + c * 8);
      }
    }
    const short* src = lK + cur * (64 * 128);
    f32x4 sf[2][4] = {};
    __builtin_amdgcn_s_setprio(1);
#pragma unroll
    for (int n = 0; n < 4; ++n) {
      bf16x8 kf[4];
#pragma unroll
      for (int fd = 0; fd < 4; ++fd) {
        int row = n * 16 + l15, jp = (l4 + fd * 4) ^ (l15 & 7);
        kf[fd] = *reinterpret_cast<const bf16x8*>(src + row * 128 + jp * 8);
      }
#pragma unroll
      for (int fd = 0; fd < 4; ++fd) {
        sf[0][n] = __builtin_amdgcn_mfma_f32_16x16x32_bf16(kf[fd], qf[0][fd], sf[0][n], 0, 0, 0);
        sf[1][n] = __builtin_amdgcn_mfma_f32_16x16x32_bf16(kf[fd], qf[1][fd], sf[1][n], 0, 0, 0);
      }
    }
    __builtin_amdgcn_s_setprio(0);
    bf16x8 vreg[8][2];
#pragma unroll
    for (int fd = 0; fd < 8; ++fd) {
      const short* vrow = Vb + (size_t)(fd * 16 + l15) * S_LEN + c0 + l4 * 8;
      vreg[fd][0] = *reinterpret_cast<const bf16x8*>(vrow);
      vreg[fd][1] = *reinterpret_cast<const bf16x8*>(vrow + 32);
    }
    const bool lastt = (kt == nkt - 1);
#pragma unroll
    for (int qa = 0; qa < 2; ++qa) {
      const int qrow_g = qt * 32 + qa * 16 + l15;
#pragma unroll
      for (int n = 0; n < 4; ++n)
#pragma unroll
        for (int r = 0; r < 4; ++r) {
          float v = sf[qa][n][r] * ATT_SCALE;
          if (lastt && (c0 + n * 16 + l4 * 4 + r) > qrow_g) v = -1e30f;
          sf[qa][n][r] = v;
        }
      float mx = sf[qa][0][0];
#pragma unroll
      for (int n = 0; n < 4; ++n)
#pragma unroll
        for (int r = 0; r < 4; ++r) mx = fmaxf(mx, sf[qa][n][r]);
      mx = fmaxf(mx, __shfl_xor(mx, 16, 64));
      mx = fmaxf(mx, __shfl_xor(mx, 32, 64));
      float mnew = fmaxf(m_run[qa], mx);
      float alpha = __expf(m_run[qa] - mnew);
      m_run[qa] = mnew;
      float ps = 0.f;
#pragma unroll
      for (int n = 0; n < 4; ++n)
#pragma unroll
        for (int r = 0; r < 4; ++r) {
          float e = __expf(sf[qa][n][r] - mnew);
          sf[qa][n][r] = e;
          ps += e;
        }
      lsum[qa] = lsum[qa] * alpha + ps;
#pragma unroll
      for (int n = 0; n < 4; ++n)
#pragma unroll
        for (int rp = 0; rp < 2; ++rp) {
          unsigned int pkv =
              ((unsigned int)(unsigned short)f2bf(sf[qa][n][rp * 2 + 1]) << 16) |
              (unsigned short)f2bf(sf[qa][n][rp * 2]);
          int kv5 = ((n & 1) << 4) + l4 * 4 + rp * 2;
          lPu[w * 1024 + qa * 512 + ((n >> 1) << 8) +
              (l15 + ((kv5 >> 3) << 4)) * 4 + ((kv5 & 7) >> 1)] = pkv;
        }
      float aO[4];
#pragma unroll
      for (int r = 0; r < 4; ++r) aO[r] = __shfl(alpha, l4 * 4 + r, 64);
#pragma unroll
      for (int fd = 0; fd < 8; ++fd) {
        o[qa][fd][0] *= aO[0]; o[qa][fd][1] *= aO[1];
        o[qa][fd][2] *= aO[2]; o[qa][fd][3] *= aO[3];
      }
    }
    asm volatile("s_waitcnt lgkmcnt(0)" ::: "memory");
    bf16x8 pf[2][2];
#pragma unroll
    for (int qa = 0; qa < 2; ++qa)
#pragma unroll
      for (int p = 0; p < 2; ++p)
        pf[qa][p] = *reinterpret_cast<const bf16x8*>(
            (const short*)lPu + (w * 1024 + qa * 512 + p * 256 + lane * 4) * 2);
    __builtin_amdgcn_s_setprio(1);
#pragma unroll
    for (int fd = 0; fd < 8; ++fd) {
      o[0][fd] = __builtin_amdgcn_mfma_f32_16x16x32_bf16(pf[0][0], vreg[fd][0], o[0][fd], 0, 0, 0);
      o[0][fd] = __builtin_amdgcn_mfma_f32_16x16x32_bf16(pf[0][1], vreg[fd][1], o[0][fd], 0, 0, 0);
      o[1][fd] = __builtin_amdgcn_mfma_f32_16x16x32_bf16(pf[1][0], vreg[fd][0], o[1][fd], 0, 0, 0);
      o[1][fd] = __builtin_amdgcn_mfma_f32_16x16x32_bf16(pf[1][1], vreg[fd][1], o[1][fd], 0, 0, 0);
    }
    __builtin_amdgcn_s_setprio(0);
    __syncthreads();
    cur ^= 1;
  }
#pragma unroll
  for (int qa = 0; qa < 2; ++qa) {
    float s = lsum[qa];
    s += __shfl_xor(s, 16, 64);
    s += __shfl_xor(s, 32, 64);
    float inv = 1.f / s;
    float iO[4];
#pragma unroll
    for (int r = 0; r < 4; ++r) iO[r] = __shfl(inv, l4 * 4 + r, 64);
#pragma unroll
    for (int fd = 0; fd < 8; ++fd)
#pragma unroll
      for (int r = 0; r < 4; ++r)
        AO[(size_t)(qt * 32 + qa * 16 + l4 * 4 + r) * HDIM + h * HD + fd * 16 + l15] =
            f2bf(o[qa][fd][r] * iO[r]);
  }
}

extern "C" void kernel_launch(void* const* d_in, const int* in_sizes, int n_in,
                              void* d_out, int out_size, void* d_ws, size_t ws_size,
                              hipStream_t stream) {
  const float* hidden = (const float*)d_in[0];
  const float* w_attn = (const float*)d_in[1];
  const float* w_proj = (const float*)d_in[2];
  const float* rcos = (const float*)d_in[3];
  const float* rsin = (const float*)d_in[4];
  float* out = (float*)d_out;
  char* ws = (char*)d_ws;

  short* Xb  = (short*)(ws);
  short* Wab = (short*)(ws + (16u << 20));
  short* Qb  = (short*)(ws + (16u << 20));
  short* Kb  = (short*)(ws + (32u << 20));
  short* Vb  = (short*)(ws + (36u << 20));
  short* Vtb = (short*)(ws + (40u << 20));
  float* QKVf = (float*)(ws + (64u << 20));
  short* Wpb = (short*)(ws + (64u << 20));
  short* AO  = Xb;

  const int nX = S_LEN * HDIM;
  const int nWa = QKVD * HDIM;
  const int nWp = HDIM * HDIM;

  hipFuncSetAttribute(reinterpret_cast<const void*>(gemm8p<256>),
                      hipFuncAttributeMaxDynamicSharedMemorySize, 131072);
  hipFuncSetAttribute(reinterpret_cast<const void*>(gemm8p<128>),
                      hipFuncAttributeMaxDynamicSharedMemorySize, 98304);

  cvt_kernel<<<nX / 1024, 256, 0, stream>>>(hidden, Xb, nX);
  cvt_kernel<<<nWa / 1024, 256, 0, stream>>>(w_attn, Wab, nWa);
  gemm8p<256><<<192, 512, 131072, stream>>>(Xb, Wab, QKVf, S_LEN, QKVD, HDIM);
  rope_kernel<<<(S_LEN * QKVD) / 256, 256, 0, stream>>>(QKVf, rcos, rsin, Qb, Kb, Vb);
  vtrans_kernel<<<dim3(S_LEN / 64, HD / 64, NKVH), 256, 0, stream>>>(Vb, Vtb);
  cvt_kernel<<<nWp / 1024, 256, 0, stream>>>(w_proj, Wpb, nWp);
  attn_kernel<<<dim3(NKVH, 64), 256, 0, stream>>>(Qb, Kb, Vtb, AO);
  gemm8p<128><<<256, 512, 98304, stream>>>(AO, Wpb, out, S_LEN, HDIM, HDIM);
}

// Round 8
// 353.010 us; speedup vs baseline: 1.5507x; 1.0383x over previous
//
#include <hip/hip_runtime.h>
#include <cstdint>
#include <cstddef>

typedef __attribute__((ext_vector_type(4))) float f32x4;
typedef __attribute__((ext_vector_type(8))) short bf16x8;

#define S_LEN 2048
#define HDIM 4096
#define QKVD 6144
#define NHEAD 32
#define NKVH 8
#define HD 128
#define ATT_SCALE 0.08838834764831845f

// fp32 -> bf16 RNE (finite inputs only)
__device__ __forceinline__ short f2bf(float f) {
  unsigned int u = __float_as_uint(f);
  u += 0x7FFFu + ((u >> 16) & 1u);
  return (short)(u >> 16);
}

// async global->LDS, 16B per lane. LDS dest = wave-uniform base + lane*16.
__device__ __forceinline__ void gl_lds16(const short* g, short* l) {
  __builtin_amdgcn_global_load_lds((const __attribute__((address_space(1))) void*)g,
                                   (__attribute__((address_space(3))) void*)l,
                                   16, 0, 0);
}

template<int N> __device__ __forceinline__ void vmw() {
  if constexpr (N == 0) asm volatile("s_waitcnt vmcnt(0)" ::: "memory");
  else if constexpr (N == 1) asm volatile("s_waitcnt vmcnt(1)" ::: "memory");
  else if constexpr (N == 2) asm volatile("s_waitcnt vmcnt(2)" ::: "memory");
  else if constexpr (N == 3) asm volatile("s_waitcnt vmcnt(3)" ::: "memory");
  else if constexpr (N == 4) asm volatile("s_waitcnt vmcnt(4)" ::: "memory");
  // N==99: no wait
}

__global__ void cvt_kernel(const float* __restrict__ in, short* __restrict__ out, int n) {
  int i = (blockIdx.x * blockDim.x + threadIdx.x) * 4;
  if (i >= n) return;
  const float4 v = *reinterpret_cast<const float4*>(in + i);
  short4 o;
  o.x = f2bf(v.x); o.y = f2bf(v.y); o.z = f2bf(v.z); o.w = f2bf(v.w);
  *reinterpret_cast<short4*>(out + i) = o;
}

// ---------------------------------------------------------------------------
// 4-phase-per-K-tile deep-pipelined GEMM: C = A[M][K] * B[N][K]^T, bf16->fp32.
// BM=128 x BN tile, BK=64, 512 threads (8 waves, 2M x 4N), LDS double-buffered.
// Phase = { ds_read quadrant frags (region guaranteed by prior vmcnt+barrier)
//           -> issue ONE stage unit of tile t+1 -> vmcnt(counted) -> s_barrier
//           -> setprio(1) MFMA cluster setprio(0) }.
// Stage units (per-thread issues): A_lo(1), B_ev(NQ), B_od(NQ), A_hi(1).
// B stripes: par selects 16-row halves of each 32-row n-block (shift-only math).
// Ordered-queue vmcnt derivation (verified against working BN=256 constants):
//   steady (2, NQ+1, 99, NQ+1), prologue NQ+1, tail (1, 0, 99, 99).
// ---------------------------------------------------------------------------
#define PHASEX(MH, NH, VM, STAGE) { \
    bf16x8 af[2][2], bfr[NQ][2]; \
    { const short* bA = lA + buf * ATILE; const short* bB = lB + buf * BTILE; \
      _Pragma("unroll") for (int m = 0; m < 2; ++m) { \
        int row = wm * 64 + (MH) * 32 + m * 16 + l15; \
        _Pragma("unroll") for (int kk = 0; kk < 2; ++kk) { \
          int slot = ((kk << 2) + l4) ^ (row & 7); \
          af[m][kk] = *reinterpret_cast<const bf16x8*>(bA + row * 64 + slot * 8); } } \
      _Pragma("unroll") for (int n = 0; n < NQ; ++n) { \
        int row = wn * (BN >> 2) + n * 32 + (NH) * 16 + l15; \
        _Pragma("unroll") for (int kk = 0; kk < 2; ++kk) { \
          int slot = ((kk << 2) + l4) ^ (row & 7); \
          bfr[n][kk] = *reinterpret_cast<const bf16x8*>(bB + row * 64 + slot * 8); } } } \
    STAGE; \
    vmw<(VM)>(); \
    __builtin_amdgcn_s_barrier(); \
    __builtin_amdgcn_sched_barrier(0); \
    __builtin_amdgcn_s_setprio(1); \
    _Pragma("unroll") for (int m = 0; m < 2; ++m) \
      _Pragma("unroll") for (int n = 0; n < NQ; ++n) \
        _Pragma("unroll") for (int kk = 0; kk < 2; ++kk) \
          acc[(MH) * 2 + m][(NH) * NQ + n] = __builtin_amdgcn_mfma_f32_16x16x32_bf16( \
              af[m][kk], bfr[n][kk], acc[(MH) * 2 + m][(NH) * NQ + n], 0, 0, 0); \
    __builtin_amdgcn_s_setprio(0); }

template<int BN>
__global__ __launch_bounds__(512, 2) void gemm8p(const short* __restrict__ A,
                                                 const short* __restrict__ B,
                                                 float* __restrict__ C,
                                                 int M, int N, int K) {
  extern __shared__ short sm[];
  constexpr int NQ = BN / 128;     // B frags per phase == B stage issues per unit
  constexpr int ATILE = 128 * 64;
  constexpr int BTILE = BN * 64;
  const int tid = threadIdx.x;
  const int wv = tid >> 6, lane = tid & 63;
  const int wm = wv >> 2, wn = wv & 3;  // 2 x 4 wave grid
  const int l15 = lane & 15, l4 = lane >> 4;
  const int nbn = N / BN;
  const int nwg = gridDim.x;
  const int bid = blockIdx.x;
  const int sbid = (bid & 7) * (nwg >> 3) + (bid >> 3);  // XCD-contiguous (nwg%8==0)
  const int tm = (sbid / nbn) * 128, tn = (sbid % nbn) * BN;
  short* lA = sm;                  // [2][128][64], swizzled
  short* lB = sm + 2 * ATILE;      // [2][BN][64], swizzled
  (void)M;

  f32x4 acc[4][2 * NQ] = {};

  // A unit: sel=0 -> rows {0-31, 64-95}; sel=1 -> {32-63, 96-127}
  auto stageA = [&](int k0, int bufi, int sel) {
    short* dst = lA + bufi * ATILE;
    int rowIdx = tid >> 3;
    int row = (rowIdx >> 5) * 64 + sel * 32 + (rowIdx & 31);
    int slot = tid & 7;
    gl_lds16(A + (size_t)(tm + row) * K + k0 + ((slot ^ (row & 7)) << 3),
             dst + row * 64 + slot * 8);
  };
  // B unit: par selects 16-row half of each 32-row block
  auto stageB = [&](int k0, int bufi, int par) {
    short* dst = lB + bufi * BTILE;
#pragma unroll
    for (int j = 0; j < NQ; ++j) {
      int rowIdx = (tid >> 3) + j * 64;
      int row = (rowIdx >> 4) * 32 + par * 16 + (rowIdx & 15);
      int slot = tid & 7;
      gl_lds16(B + (size_t)(tn + row) * K + k0 + ((slot ^ (row & 7)) << 3),
               dst + row * 64 + slot * 8);
    }
  };

  // prologue: tile 0, issue order = consume order
  stageA(0, 0, 0);
  stageB(0, 0, 0);
  stageB(0, 0, 1);
  stageA(0, 0, 1);
  vmw<NQ + 1>();
  __builtin_amdgcn_s_barrier();
  __builtin_amdgcn_sched_barrier(0);

  const int KT = K >> 6;
  for (int t = 0; t < KT - 1; ++t) {
    const int buf = t & 1, nbuf = buf ^ 1, nk0 = (t + 1) << 6;
    PHASEX(0, 0, 2,      stageA(nk0, nbuf, 0))
    PHASEX(0, 1, NQ + 1, stageB(nk0, nbuf, 0))
    PHASEX(1, 0, 99,     stageB(nk0, nbuf, 1))
    PHASEX(1, 1, NQ + 1, stageA(nk0, nbuf, 1))
  }
  {  // tail tile: no staging; drain progressively
    const int buf = (KT - 1) & 1;
    PHASEX(0, 0, 1,  (void)0)
    PHASEX(0, 1, 0,  (void)0)
    PHASEX(1, 0, 99, (void)0)
    PHASEX(1, 1, 99, (void)0)
  }
#pragma unroll
  for (int mg = 0; mg < 4; ++mg)
#pragma unroll
    for (int NH = 0; NH < 2; ++NH)
#pragma unroll
      for (int n = 0; n < NQ; ++n)
#pragma unroll
        for (int r = 0; r < 4; ++r) {
          int row = tm + wm * 64 + mg * 16 + l4 * 4 + r;
          int col = tn + wn * (BN >> 2) + n * 32 + NH * 16 + l15;
          C[(size_t)row * N + col] = acc[mg][NH * NQ + n][r];
        }
}

// rope pass 2: one thread per (s,g,part,d<64) pair -> each qkv elem read once.
// cos[d+64]==cos[d], sin likewise (emb = concat(freqs,freqs)).
__global__ void rope2_kernel(const float* __restrict__ qkv,
                             const float* __restrict__ cb,
                             const float* __restrict__ sb,
                             short* __restrict__ Q,
                             short* __restrict__ Kx) {
  int tid = blockIdx.x * blockDim.x + threadIdx.x;  // S*NKV*5*64
  int dh = tid & 63;
  int t2 = tid >> 6;
  int part = t2 % 5;            // 0..3 = q heads in group, 4 = k
  int t3 = t2 / 5;
  int g = t3 & 7;
  int s = t3 >> 3;
  const float* base = qkv + (size_t)s * QKVD + g * 768 + part * 128;
  float v1 = base[dh], v2 = base[dh + 64];
  float c = cb[s * HD + dh], sn = sb[s * HD + dh];
  float o1 = v1 * c - v2 * sn;
  float o2 = v2 * c + v1 * sn;
  short* dst = (part < 4) ? (Q + ((size_t)(g * 4 + part) * S_LEN + s) * HD)
                          : (Kx + ((size_t)g * S_LEN + s) * HD);
  dst[dh] = f2bf(o1);
  dst[dh + 64] = f2bf(o2);
}

// V region of qkv (fp32) -> Vt [NKVH][HD][S] bf16, 64x64 LDS tiles
__global__ __launch_bounds__(256) void vtrans2_kernel(const float* __restrict__ qkv,
                                                      short* __restrict__ Vt) {
  __shared__ short tile[64][72];
  const int kvh = blockIdx.z;
  const int s0 = blockIdx.x * 64, d0 = blockIdx.y * 64;
  const int t = threadIdx.x;
#pragma unroll
  for (int i = 0; i < 4; ++i) {
    int c = t + i * 256;  // [0,1024)
    int sl = c >> 4, dl = (c & 15) * 4;
    const float4 v = *reinterpret_cast<const float4*>(
        qkv + (size_t)(s0 + sl) * QKVD + kvh * 768 + 640 + d0 + dl);
    tile[sl][dl] = f2bf(v.x); tile[sl][dl + 1] = f2bf(v.y);
    tile[sl][dl + 2] = f2bf(v.z); tile[sl][dl + 3] = f2bf(v.w);
  }
  __syncthreads();
  short* Vtb = Vt + (size_t)kvh * HD * S_LEN;
#pragma unroll
  for (int i = 0; i < 2; ++i) {
    int dl = i * 32 + (t >> 3), sl = (t & 7) * 8;
    bf16x8 o;
#pragma unroll
    for (int j = 0; j < 8; ++j) o[j] = tile[sl + j][dl];
    *reinterpret_cast<bf16x8*>(Vtb + (size_t)(d0 + dl) * S_LEN + s0 + sl) = o;
  }
}

// flash attention v5 (unchanged, passing)
__global__ __launch_bounds__(256, 2) void attn_kernel(const short* __restrict__ Q,
                                                      const short* __restrict__ Kx,
                                                      const short* __restrict__ Vt,
                                                      short* __restrict__ AO) {
  __shared__ short lK[2 * 64 * 128];
  __shared__ unsigned int lPu[4 * 2 * 512];
  const int tt = threadIdx.x;
  const int w = tt >> 6, lane = tt & 63;
  const int l15 = lane & 15, l4 = lane >> 4;
  const int kvh = blockIdx.x;
  const int y = blockIdx.y;
  const int qt = (y < 32) ? (2 * y) : (127 - 2 * y);
  const int h = kvh * 4 + w;

  bf16x8 qf[2][4];
#pragma unroll
  for (int qa = 0; qa < 2; ++qa) {
    const short* qrow = Q + ((size_t)h * S_LEN + qt * 32 + qa * 16 + l15) * HD + l4 * 8;
#pragma unroll
    for (int fd = 0; fd < 4; ++fd)
      qf[qa][fd] = *reinterpret_cast<const bf16x8*>(qrow + fd * 32);
  }

  f32x4 o[2][8] = {};
  float m_run[2] = {-1e30f, -1e30f};
  float lsum[2] = {0.f, 0.f};

  const short* Kb = Kx + (size_t)kvh * S_LEN * HD;
  const short* Vb = Vt + (size_t)kvh * HD * S_LEN;
  const int nkt = (qt >> 1) + 1;

#pragma unroll
  for (int i = 0; i < 4; ++i) {
    int c = tt + i * 256, row = c >> 4, jj = (c & 15) ^ (row & 7);
    gl_lds16(Kb + (size_t)row * HD + jj * 8, lK + c * 8);
  }
  __syncthreads();

  int cur = 0;
  for (int kt = 0; kt < nkt; ++kt) {
    const int c0 = kt * 64;
    if (kt + 1 < nkt) {
      const short* Kg = Kb + (size_t)(c0 + 64) * HD;
      short* dst = lK + (cur ^ 1) * (64 * 128);
#pragma unroll
      for (int i = 0; i < 4; ++i) {
        int c = tt + i * 256, row = c >> 4, jj = (c & 15) ^ (row & 7);
        gl_lds16(Kg + (size_t)row * HD + jj * 8, dst + c * 8);
      }
    }
    const short* src = lK + cur * (64 * 128);
    f32x4 sf[2][4] = {};
    __builtin_amdgcn_s_setprio(1);
#pragma unroll
    for (int n = 0; n < 4; ++n) {
      bf16x8 kf[4];
#pragma unroll
      for (int fd = 0; fd < 4; ++fd) {
        int row = n * 16 + l15, jp = (l4 + fd * 4) ^ (l15 & 7);
        kf[fd] = *reinterpret_cast<const bf16x8*>(src + row * 128 + jp * 8);
      }
#pragma unroll
      for (int fd = 0; fd < 4; ++fd) {
        sf[0][n] = __builtin_amdgcn_mfma_f32_16x16x32_bf16(kf[fd], qf[0][fd], sf[0][n], 0, 0, 0);
        sf[1][n] = __builtin_amdgcn_mfma_f32_16x16x32_bf16(kf[fd], qf[1][fd], sf[1][n], 0, 0, 0);
      }
    }
    __builtin_amdgcn_s_setprio(0);
    bf16x8 vreg[8][2];
#pragma unroll
    for (int fd = 0; fd < 8; ++fd) {
      const short* vrow = Vb + (size_t)(fd * 16 + l15) * S_LEN + c0 + l4 * 8;
      vreg[fd][0] = *reinterpret_cast<const bf16x8*>(vrow);
      vreg[fd][1] = *reinterpret_cast<const bf16x8*>(vrow + 32);
    }
    const bool lastt = (kt == nkt - 1);
#pragma unroll
    for (int qa = 0; qa < 2; ++qa) {
      const int qrow_g = qt * 32 + qa * 16 + l15;
#pragma unroll
      for (int n = 0; n < 4; ++n)
#pragma unroll
        for (int r = 0; r < 4; ++r) {
          float v = sf[qa][n][r] * ATT_SCALE;
          if (lastt && (c0 + n * 16 + l4 * 4 + r) > qrow_g) v = -1e30f;
          sf[qa][n][r] = v;
        }
      float mx = sf[qa][0][0];
#pragma unroll
      for (int n = 0; n < 4; ++n)
#pragma unroll
        for (int r = 0; r < 4; ++r) mx = fmaxf(mx, sf[qa][n][r]);
      mx = fmaxf(mx, __shfl_xor(mx, 16, 64));
      mx = fmaxf(mx, __shfl_xor(mx, 32, 64));
      float mnew = fmaxf(m_run[qa], mx);
      float alpha = __expf(m_run[qa] - mnew);
      m_run[qa] = mnew;
      float ps = 0.f;
#pragma unroll
      for (int n = 0; n < 4; ++n)
#pragma unroll
        for (int r = 0; r < 4; ++r) {
          float e = __expf(sf[qa][n][r] - mnew);
          sf[qa][n][r] = e;
          ps += e;
        }
      lsum[qa] = lsum[qa] * alpha + ps;
#pragma unroll
      for (int n = 0; n < 4; ++n)
#pragma unroll
        for (int rp = 0; rp < 2; ++rp) {
          unsigned int pkv =
              ((unsigned int)(unsigned short)f2bf(sf[qa][n][rp * 2 + 1]) << 16) |
              (unsigned short)f2bf(sf[qa][n][rp * 2]);
          int kv5 = ((n & 1) << 4) + l4 * 4 + rp * 2;
          lPu[w * 1024 + qa * 512 + ((n >> 1) << 8) +
              (l15 + ((kv5 >> 3) << 4)) * 4 + ((kv5 & 7) >> 1)] = pkv;
        }
      float aO[4];
#pragma unroll
      for (int r = 0; r < 4; ++r) aO[r] = __shfl(alpha, l4 * 4 + r, 64);
#pragma unroll
      for (int fd = 0; fd < 8; ++fd) {
        o[qa][fd][0] *= aO[0]; o[qa][fd][1] *= aO[1];
        o[qa][fd][2] *= aO[2]; o[qa][fd][3] *= aO[3];
      }
    }
    asm volatile("s_waitcnt lgkmcnt(0)" ::: "memory");
    bf16x8 pf[2][2];
#pragma unroll
    for (int qa = 0; qa < 2; ++qa)
#pragma unroll
      for (int p = 0; p < 2; ++p)
        pf[qa][p] = *reinterpret_cast<const bf16x8*>(
            (const short*)lPu + (w * 1024 + qa * 512 + p * 256 + lane * 4) * 2);
    __builtin_amdgcn_s_setprio(1);
#pragma unroll
    for (int fd = 0; fd < 8; ++fd) {
      o[0][fd] = __builtin_amdgcn_mfma_f32_16x16x32_bf16(pf[0][0], vreg[fd][0], o[0][fd], 0, 0, 0);
      o[0][fd] = __builtin_amdgcn_mfma_f32_16x16x32_bf16(pf[0][1], vreg[fd][1], o[0][fd], 0, 0, 0);
      o[1][fd] = __builtin_amdgcn_mfma_f32_16x16x32_bf16(pf[1][0], vreg[fd][0], o[1][fd], 0, 0, 0);
      o[1][fd] = __builtin_amdgcn_mfma_f32_16x16x32_bf16(pf[1][1], vreg[fd][1], o[1][fd], 0, 0, 0);
    }
    __builtin_amdgcn_s_setprio(0);
    __syncthreads();
    cur ^= 1;
  }
#pragma unroll
  for (int qa = 0; qa < 2; ++qa) {
    float s = lsum[qa];
    s += __shfl_xor(s, 16, 64);
    s += __shfl_xor(s, 32, 64);
    float inv = 1.f / s;
    float iO[4];
#pragma unroll
    for (int r = 0; r < 4; ++r) iO[r] = __shfl(inv, l4 * 4 + r, 64);
#pragma unroll
    for (int fd = 0; fd < 8; ++fd)
#pragma unroll
      for (int r = 0; r < 4; ++r)
        AO[(size_t)(qt * 32 + qa * 16 + l4 * 4 + r) * HDIM + h * HD + fd * 16 + l15] =
            f2bf(o[qa][fd][r] * iO[r]);
  }
}

extern "C" void kernel_launch(void* const* d_in, const int* in_sizes, int n_in,
                              void* d_out, int out_size, void* d_ws, size_t ws_size,
                              hipStream_t stream) {
  const float* hidden = (const float*)d_in[0];
  const float* w_attn = (const float*)d_in[1];
  const float* w_proj = (const float*)d_in[2];
  const float* rcos = (const float*)d_in[3];
  const float* rsin = (const float*)d_in[4];
  float* out = (float*)d_out;
  char* ws = (char*)d_ws;

  // workspace layout (overlaid):
  //  [0,16Mi)    Xb (bf16 X)          -> reused as AO after gemm1
  //  [16,64Mi)   Wab (bf16 w_attn)    -> after gemm1: Qb[16,32) Kb[32,36) Vtb[40,44.2)
  //  [64,~114Mi) QKVf (fp32 qkv)      -> reused as Wpb (bf16 w_proj) after rope2+vtrans2
  short* Xb  = (short*)(ws);
  short* Wab = (short*)(ws + (16u << 20));
  short* Qb  = (short*)(ws + (16u << 20));
  short* Kb  = (short*)(ws + (32u << 20));
  short* Vtb = (short*)(ws + (40u << 20));
  float* QKVf = (float*)(ws + (64u << 20));
  short* Wpb = (short*)(ws + (64u << 20));
  short* AO  = Xb;

  const int nX = S_LEN * HDIM;
  const int nWa = QKVD * HDIM;
  const int nWp = HDIM * HDIM;

  hipFuncSetAttribute(reinterpret_cast<const void*>(gemm8p<384>),
                      hipFuncAttributeMaxDynamicSharedMemorySize, 131072);
  hipFuncSetAttribute(reinterpret_cast<const void*>(gemm8p<256>),
                      hipFuncAttributeMaxDynamicSharedMemorySize, 98304);

  cvt_kernel<<<nX / 1024, 256, 0, stream>>>(hidden, Xb, nX);
  cvt_kernel<<<nWa / 1024, 256, 0, stream>>>(w_attn, Wab, nWa);
  gemm8p<384><<<256, 512, 131072, stream>>>(Xb, Wab, QKVf, S_LEN, QKVD, HDIM);
  rope2_kernel<<<(S_LEN * NKVH * 5 * 64) / 256, 256, 0, stream>>>(QKVf, rcos, rsin, Qb, Kb);
  vtrans2_kernel<<<dim3(S_LEN / 64, HD / 64, NKVH), 256, 0, stream>>>(QKVf, Vtb);
  cvt_kernel<<<nWp / 1024, 256, 0, stream>>>(w_proj, Wpb, nWp);
  attn_kernel<<<dim3(NKVH, 64), 256, 0, stream>>>(Qb, Kb, Vtb, AO);
  gemm8p<256><<<256, 512, 98304, stream>>>(AO, Wpb, out, S_LEN, HDIM, HDIM);
}

// Round 9
// 346.486 us; speedup vs baseline: 1.5799x; 1.0188x over previous
//
#include <hip/hip_runtime.h>
#include <cstdint>
#include <cstddef>

typedef __attribute__((ext_vector_type(4))) float f32x4;
typedef __attribute__((ext_vector_type(8))) short bf16x8;

#define S_LEN 2048
#define HDIM 4096
#define QKVD 6144
#define NHEAD 32
#define NKVH 8
#define HD 128
// Q pre-scaled by ATT_SCALE * log2(e): softmax runs in exp2 domain
#define QPRE 0.12751744631123533f

// fp32 -> bf16 RNE (finite inputs only)
__device__ __forceinline__ short f2bf(float f) {
  unsigned int u = __float_as_uint(f);
  u += 0x7FFFu + ((u >> 16) & 1u);
  return (short)(u >> 16);
}
__device__ __forceinline__ float bf2f(short s) {
  return __uint_as_float((unsigned int)(unsigned short)s << 16);
}

// async global->LDS, 16B per lane. LDS dest = wave-uniform base + lane*16.
__device__ __forceinline__ void gl_lds16(const short* g, short* l) {
  __builtin_amdgcn_global_load_lds((const __attribute__((address_space(1))) void*)g,
                                   (__attribute__((address_space(3))) void*)l,
                                   16, 0, 0);
}

template<int N> __device__ __forceinline__ void vmw() {
  if constexpr (N == 0) asm volatile("s_waitcnt vmcnt(0)" ::: "memory");
  else if constexpr (N == 1) asm volatile("s_waitcnt vmcnt(1)" ::: "memory");
  else if constexpr (N == 2) asm volatile("s_waitcnt vmcnt(2)" ::: "memory");
  else if constexpr (N == 3) asm volatile("s_waitcnt vmcnt(3)" ::: "memory");
  else if constexpr (N == 4) asm volatile("s_waitcnt vmcnt(4)" ::: "memory");
  // N==99: no wait
}

__global__ void cvt_kernel(const float* __restrict__ in, short* __restrict__ out, int n) {
  int i = (blockIdx.x * blockDim.x + threadIdx.x) * 4;
  if (i >= n) return;
  const float4 v = *reinterpret_cast<const float4*>(in + i);
  short4 o;
  o.x = f2bf(v.x); o.y = f2bf(v.y); o.z = f2bf(v.z); o.w = f2bf(v.w);
  *reinterpret_cast<short4*>(out + i) = o;
}

// ---------------------------------------------------------------------------
// 4-phase-per-K-tile deep-pipelined GEMM (unchanged from round 8, verified)
// ---------------------------------------------------------------------------
#define PHASEX(MH, NH, VM, STAGE) { \
    bf16x8 af[2][2], bfr[NQ][2]; \
    { const short* bA = lA + buf * ATILE; const short* bB = lB + buf * BTILE; \
      _Pragma("unroll") for (int m = 0; m < 2; ++m) { \
        int row = wm * 64 + (MH) * 32 + m * 16 + l15; \
        _Pragma("unroll") for (int kk = 0; kk < 2; ++kk) { \
          int slot = ((kk << 2) + l4) ^ (row & 7); \
          af[m][kk] = *reinterpret_cast<const bf16x8*>(bA + row * 64 + slot * 8); } } \
      _Pragma("unroll") for (int n = 0; n < NQ; ++n) { \
        int row = wn * (BN >> 2) + n * 32 + (NH) * 16 + l15; \
        _Pragma("unroll") for (int kk = 0; kk < 2; ++kk) { \
          int slot = ((kk << 2) + l4) ^ (row & 7); \
          bfr[n][kk] = *reinterpret_cast<const bf16x8*>(bB + row * 64 + slot * 8); } } } \
    STAGE; \
    vmw<(VM)>(); \
    __builtin_amdgcn_s_barrier(); \
    __builtin_amdgcn_sched_barrier(0); \
    __builtin_amdgcn_s_setprio(1); \
    _Pragma("unroll") for (int m = 0; m < 2; ++m) \
      _Pragma("unroll") for (int n = 0; n < NQ; ++n) \
        _Pragma("unroll") for (int kk = 0; kk < 2; ++kk) \
          acc[(MH) * 2 + m][(NH) * NQ + n] = __builtin_amdgcn_mfma_f32_16x16x32_bf16( \
              af[m][kk], bfr[n][kk], acc[(MH) * 2 + m][(NH) * NQ + n], 0, 0, 0); \
    __builtin_amdgcn_s_setprio(0); }

template<int BN>
__global__ __launch_bounds__(512, 2) void gemm8p(const short* __restrict__ A,
                                                 const short* __restrict__ B,
                                                 float* __restrict__ C,
                                                 int M, int N, int K) {
  extern __shared__ short sm[];
  constexpr int NQ = BN / 128;
  constexpr int ATILE = 128 * 64;
  constexpr int BTILE = BN * 64;
  const int tid = threadIdx.x;
  const int wv = tid >> 6, lane = tid & 63;
  const int wm = wv >> 2, wn = wv & 3;
  const int l15 = lane & 15, l4 = lane >> 4;
  const int nbn = N / BN;
  const int nwg = gridDim.x;
  const int bid = blockIdx.x;
  const int sbid = (bid & 7) * (nwg >> 3) + (bid >> 3);
  const int tm = (sbid / nbn) * 128, tn = (sbid % nbn) * BN;
  short* lA = sm;
  short* lB = sm + 2 * ATILE;
  (void)M;

  f32x4 acc[4][2 * NQ] = {};

  auto stageA = [&](int k0, int bufi, int sel) {
    short* dst = lA + bufi * ATILE;
    int rowIdx = tid >> 3;
    int row = (rowIdx >> 5) * 64 + sel * 32 + (rowIdx & 31);
    int slot = tid & 7;
    gl_lds16(A + (size_t)(tm + row) * K + k0 + ((slot ^ (row & 7)) << 3),
             dst + row * 64 + slot * 8);
  };
  auto stageB = [&](int k0, int bufi, int par) {
    short* dst = lB + bufi * BTILE;
#pragma unroll
    for (int j = 0; j < NQ; ++j) {
      int rowIdx = (tid >> 3) + j * 64;
      int row = (rowIdx >> 4) * 32 + par * 16 + (rowIdx & 15);
      int slot = tid & 7;
      gl_lds16(B + (size_t)(tn + row) * K + k0 + ((slot ^ (row & 7)) << 3),
               dst + row * 64 + slot * 8);
    }
  };

  stageA(0, 0, 0);
  stageB(0, 0, 0);
  stageB(0, 0, 1);
  stageA(0, 0, 1);
  vmw<NQ + 1>();
  __builtin_amdgcn_s_barrier();
  __builtin_amdgcn_sched_barrier(0);

  const int KT = K >> 6;
  for (int t = 0; t < KT - 1; ++t) {
    const int buf = t & 1, nbuf = buf ^ 1, nk0 = (t + 1) << 6;
    PHASEX(0, 0, 2,      stageA(nk0, nbuf, 0))
    PHASEX(0, 1, NQ + 1, stageB(nk0, nbuf, 0))
    PHASEX(1, 0, 99,     stageB(nk0, nbuf, 1))
    PHASEX(1, 1, NQ + 1, stageA(nk0, nbuf, 1))
  }
  {
    const int buf = (KT - 1) & 1;
    PHASEX(0, 0, 1,  (void)0)
    PHASEX(0, 1, 0,  (void)0)
    PHASEX(1, 0, 99, (void)0)
    PHASEX(1, 1, 99, (void)0)
  }
#pragma unroll
  for (int mg = 0; mg < 4; ++mg)
#pragma unroll
    for (int NH = 0; NH < 2; ++NH)
#pragma unroll
      for (int n = 0; n < NQ; ++n)
#pragma unroll
        for (int r = 0; r < 4; ++r) {
          int row = tm + wm * 64 + mg * 16 + l4 * 4 + r;
          int col = tn + wn * (BN >> 2) + n * 32 + NH * 16 + l15;
          C[(size_t)row * N + col] = acc[mg][NH * NQ + n][r];
        }
}

// rope pass 2: one thread per (s,g,part,d<64) pair. Q pre-scaled by QPRE so
// attention softmax runs in the exp2 domain with no per-element scale.
__global__ void rope2_kernel(const float* __restrict__ qkv,
                             const float* __restrict__ cb,
                             const float* __restrict__ sb,
                             short* __restrict__ Q,
                             short* __restrict__ Kx) {
  int tid = blockIdx.x * blockDim.x + threadIdx.x;
  int dh = tid & 63;
  int t2 = tid >> 6;
  int part = t2 % 5;
  int t3 = t2 / 5;
  int g = t3 & 7;
  int s = t3 >> 3;
  const float* base = qkv + (size_t)s * QKVD + g * 768 + part * 128;
  float v1 = base[dh], v2 = base[dh + 64];
  float c = cb[s * HD + dh], sn = sb[s * HD + dh];
  float o1 = v1 * c - v2 * sn;
  float o2 = v2 * c + v1 * sn;
  if (part < 4) {
    o1 *= QPRE; o2 *= QPRE;
    short* dst = Q + ((size_t)(g * 4 + part) * S_LEN + s) * HD;
    dst[dh] = f2bf(o1);
    dst[dh + 64] = f2bf(o2);
  } else {
    short* dst = Kx + ((size_t)g * S_LEN + s) * HD;
    dst[dh] = f2bf(o1);
    dst[dh + 64] = f2bf(o2);
  }
}

// V region of qkv (fp32) -> Vt [NKVH][HD][S] bf16, 64x64 LDS tiles
__global__ __launch_bounds__(256) void vtrans2_kernel(const float* __restrict__ qkv,
                                                      short* __restrict__ Vt) {
  __shared__ short tile[64][72];
  const int kvh = blockIdx.z;
  const int s0 = blockIdx.x * 64, d0 = blockIdx.y * 64;
  const int t = threadIdx.x;
#pragma unroll
  for (int i = 0; i < 4; ++i) {
    int c = t + i * 256;
    int sl = c >> 4, dl = (c & 15) * 4;
    const float4 v = *reinterpret_cast<const float4*>(
        qkv + (size_t)(s0 + sl) * QKVD + kvh * 768 + 640 + d0 + dl);
    tile[sl][dl] = f2bf(v.x); tile[sl][dl + 1] = f2bf(v.y);
    tile[sl][dl + 2] = f2bf(v.z); tile[sl][dl + 3] = f2bf(v.w);
  }
  __syncthreads();
  short* Vtb = Vt + (size_t)kvh * HD * S_LEN;
#pragma unroll
  for (int i = 0; i < 2; ++i) {
    int dl = i * 32 + (t >> 3), sl = (t & 7) * 8;
    bf16x8 o;
#pragma unroll
    for (int j = 0; j < 8; ++j) o[j] = tile[sl + j][dl];
    *reinterpret_cast<bf16x8*>(Vtb + (size_t)(d0 + dl) * S_LEN + s0 + sl) = o;
  }
}

// flash attention v6: kv-split flash-decoding. Grid (kvh, y, split).
// qt = 63-y (big blocks launch first -> dynamic refill smooths the tail).
// Split z handles tiles [t0,t1) of nkt; writes UNNORMALIZED O partial (bf16)
// + per-row (m, lsum) stats. exp2-domain softmax (Q pre-scaled by QPRE).
__global__ __launch_bounds__(256, 2) void attn_kernel(const short* __restrict__ Q,
                                                      const short* __restrict__ Kx,
                                                      const short* __restrict__ Vt,
                                                      short* __restrict__ part0,
                                                      short* __restrict__ part1,
                                                      float2* __restrict__ stat0,
                                                      float2* __restrict__ stat1) {
  __shared__ short lK[2 * 64 * 128];
  __shared__ unsigned int lPu[4 * 2 * 512];
  const int tt = threadIdx.x;
  const int w = tt >> 6, lane = tt & 63;
  const int l15 = lane & 15, l4 = lane >> 4;
  const int kvh = blockIdx.x;
  const int qt = 63 - blockIdx.y;
  const int z = blockIdx.z;
  const int h = kvh * 4 + w;
  short* pout = z ? part1 : part0;
  float2* sout = z ? stat1 : stat0;

  const int nkt = (qt >> 1) + 1;
  const int ts = (nkt + 1) >> 1;
  const int t0 = z ? ts : 0;
  const int t1 = z ? nkt : ts;

  f32x4 o[2][8] = {};
  float m_run[2] = {-1e30f, -1e30f};
  float lsum[2] = {0.f, 0.f};

  if (t0 < t1) {
    bf16x8 qf[2][4];
#pragma unroll
    for (int qa = 0; qa < 2; ++qa) {
      const short* qrow = Q + ((size_t)h * S_LEN + qt * 32 + qa * 16 + l15) * HD + l4 * 8;
#pragma unroll
      for (int fd = 0; fd < 4; ++fd)
        qf[qa][fd] = *reinterpret_cast<const bf16x8*>(qrow + fd * 32);
    }
    const short* Kb = Kx + (size_t)kvh * S_LEN * HD;
    const short* Vb = Vt + (size_t)kvh * HD * S_LEN;

    // prologue: stage tile t0
    {
      const short* Kg = Kb + (size_t)(t0 * 64) * HD;
#pragma unroll
      for (int i = 0; i < 4; ++i) {
        int c = tt + i * 256, row = c >> 4, jj = (c & 15) ^ (row & 7);
        gl_lds16(Kg + (size_t)row * HD + jj * 8, lK + c * 8);
      }
    }
    __syncthreads();

    int cur = 0;
    for (int kt = t0; kt < t1; ++kt) {
      const int c0 = kt * 64;
      if (kt + 1 < t1) {
        const short* Kg = Kb + (size_t)(c0 + 64) * HD;
        short* dst = lK + (cur ^ 1) * (64 * 128);
#pragma unroll
        for (int i = 0; i < 4; ++i) {
          int c = tt + i * 256, row = c >> 4, jj = (c & 15) ^ (row & 7);
          gl_lds16(Kg + (size_t)row * HD + jj * 8, dst + c * 8);
        }
      }
      const short* src = lK + cur * (64 * 128);
      f32x4 sf[2][4] = {};
      __builtin_amdgcn_s_setprio(1);
#pragma unroll
      for (int n = 0; n < 4; ++n) {
        bf16x8 kf[4];
#pragma unroll
        for (int fd = 0; fd < 4; ++fd) {
          int row = n * 16 + l15, jp = (l4 + fd * 4) ^ (l15 & 7);
          kf[fd] = *reinterpret_cast<const bf16x8*>(src + row * 128 + jp * 8);
        }
#pragma unroll
        for (int fd = 0; fd < 4; ++fd) {
          sf[0][n] = __builtin_amdgcn_mfma_f32_16x16x32_bf16(kf[fd], qf[0][fd], sf[0][n], 0, 0, 0);
          sf[1][n] = __builtin_amdgcn_mfma_f32_16x16x32_bf16(kf[fd], qf[1][fd], sf[1][n], 0, 0, 0);
        }
      }
      __builtin_amdgcn_s_setprio(0);
      bf16x8 vreg[8][2];
#pragma unroll
      for (int fd = 0; fd < 8; ++fd) {
        const short* vrow = Vb + (size_t)(fd * 16 + l15) * S_LEN + c0 + l4 * 8;
        vreg[fd][0] = *reinterpret_cast<const bf16x8*>(vrow);
        vreg[fd][1] = *reinterpret_cast<const bf16x8*>(vrow + 32);
      }
      const bool lastt = (kt == nkt - 1);
#pragma unroll
      for (int qa = 0; qa < 2; ++qa) {
        if (lastt) {  // wave-uniform: only the diagonal tile pays for masking
          const int qrow_g = qt * 32 + qa * 16 + l15;
#pragma unroll
          for (int n = 0; n < 4; ++n)
#pragma unroll
            for (int r = 0; r < 4; ++r)
              if ((c0 + n * 16 + l4 * 4 + r) > qrow_g) sf[qa][n][r] = -1e30f;
        }
        float mx = sf[qa][0][0];
#pragma unroll
        for (int n = 0; n < 4; ++n)
#pragma unroll
          for (int r = 0; r < 4; ++r) mx = fmaxf(mx, sf[qa][n][r]);
        mx = fmaxf(mx, __shfl_xor(mx, 16, 64));
        mx = fmaxf(mx, __shfl_xor(mx, 32, 64));
        float mnew = fmaxf(m_run[qa], mx);
        float alpha = exp2f(m_run[qa] - mnew);
        m_run[qa] = mnew;
        float ps = 0.f;
#pragma unroll
        for (int n = 0; n < 4; ++n)
#pragma unroll
          for (int r = 0; r < 4; ++r) {
            float e = exp2f(sf[qa][n][r] - mnew);
            sf[qa][n][r] = e;
            ps += e;
          }
        lsum[qa] = lsum[qa] * alpha + ps;
#pragma unroll
        for (int n = 0; n < 4; ++n)
#pragma unroll
          for (int rp = 0; rp < 2; ++rp) {
            unsigned int pkv =
                ((unsigned int)(unsigned short)f2bf(sf[qa][n][rp * 2 + 1]) << 16) |
                (unsigned short)f2bf(sf[qa][n][rp * 2]);
            int kv5 = ((n & 1) << 4) + l4 * 4 + rp * 2;
            lPu[w * 1024 + qa * 512 + ((n >> 1) << 8) +
                (l15 + ((kv5 >> 3) << 4)) * 4 + ((kv5 & 7) >> 1)] = pkv;
          }
        float aO[4];
#pragma unroll
        for (int r = 0; r < 4; ++r) aO[r] = __shfl(alpha, l4 * 4 + r, 64);
#pragma unroll
        for (int fd = 0; fd < 8; ++fd) {
          o[qa][fd][0] *= aO[0]; o[qa][fd][1] *= aO[1];
          o[qa][fd][2] *= aO[2]; o[qa][fd][3] *= aO[3];
        }
      }
      asm volatile("s_waitcnt lgkmcnt(0)" ::: "memory");
      bf16x8 pf[2][2];
#pragma unroll
      for (int qa = 0; qa < 2; ++qa)
#pragma unroll
        for (int p = 0; p < 2; ++p)
          pf[qa][p] = *reinterpret_cast<const bf16x8*>(
              (const short*)lPu + (w * 1024 + qa * 512 + p * 256 + lane * 4) * 2);
      __builtin_amdgcn_s_setprio(1);
#pragma unroll
      for (int fd = 0; fd < 8; ++fd) {
        o[0][fd] = __builtin_amdgcn_mfma_f32_16x16x32_bf16(pf[0][0], vreg[fd][0], o[0][fd], 0, 0, 0);
        o[0][fd] = __builtin_amdgcn_mfma_f32_16x16x32_bf16(pf[0][1], vreg[fd][1], o[0][fd], 0, 0, 0);
        o[1][fd] = __builtin_amdgcn_mfma_f32_16x16x32_bf16(pf[1][0], vreg[fd][0], o[1][fd], 0, 0, 0);
        o[1][fd] = __builtin_amdgcn_mfma_f32_16x16x32_bf16(pf[1][1], vreg[fd][1], o[1][fd], 0, 0, 0);
      }
      __builtin_amdgcn_s_setprio(0);
      __syncthreads();
      cur ^= 1;
    }
  }
  // epilogue: reduce lsum, write stats + unnormalized partial O
#pragma unroll
  for (int qa = 0; qa < 2; ++qa) {
    float s = lsum[qa];
    s += __shfl_xor(s, 16, 64);
    s += __shfl_xor(s, 32, 64);
    if (l4 == 0)
      sout[(size_t)h * S_LEN + qt * 32 + qa * 16 + l15] = make_float2(m_run[qa], s);
#pragma unroll
    for (int fd = 0; fd < 8; ++fd)
#pragma unroll
      for (int r = 0; r < 4; ++r)
        pout[((size_t)h * S_LEN + qt * 32 + qa * 16 + l4 * 4 + r) * HD + fd * 16 + l15] =
            f2bf(o[qa][fd][r]);
  }
}

// merge the two kv-split partials -> AO [S][NH*HD]
__global__ __launch_bounds__(256) void combine_kernel(const short* __restrict__ p0,
                                                      const short* __restrict__ p1,
                                                      const float2* __restrict__ st0,
                                                      const float2* __restrict__ st1,
                                                      short* __restrict__ AO) {
  int idx = (blockIdx.x * 256 + threadIdx.x) * 8;  // over NH*S*HD
  int h = idx >> 18;                 // S*HD = 2^18
  int rem = idx & ((1 << 18) - 1);
  int s = rem >> 7, d = rem & 127;
  float2 a = st0[(size_t)h * S_LEN + s];
  float2 b = st1[(size_t)h * S_LEN + s];
  float M = fmaxf(a.x, b.x);
  float w0 = exp2f(a.x - M), w1 = exp2f(b.x - M);
  float inv = 1.f / (a.y * w0 + b.y * w1);
  w0 *= inv; w1 *= inv;
  bf16x8 v0 = *reinterpret_cast<const bf16x8*>(p0 + idx);
  bf16x8 v1 = *reinterpret_cast<const bf16x8*>(p1 + idx);
  bf16x8 ov;
#pragma unroll
  for (int j = 0; j < 8; ++j)
    ov[j] = f2bf(bf2f(v0[j]) * w0 + bf2f(v1[j]) * w1);
  *reinterpret_cast<bf16x8*>(AO + (size_t)s * HDIM + h * HD + d) = ov;
}

extern "C" void kernel_launch(void* const* d_in, const int* in_sizes, int n_in,
                              void* d_out, int out_size, void* d_ws, size_t ws_size,
                              hipStream_t stream) {
  const float* hidden = (const float*)d_in[0];
  const float* w_attn = (const float*)d_in[1];
  const float* w_proj = (const float*)d_in[2];
  const float* rcos = (const float*)d_in[3];
  const float* rsin = (const float*)d_in[4];
  float* out = (float*)d_out;
  char* ws = (char*)d_ws;

  // workspace layout (overlaid, ~112 MiB):
  //  [0,16Mi)    Xb (bf16 X) -> dead after gemm1 -> AO (combine output)
  //  [16,64Mi)   Wab -> after gemm1: Qb[16,32) Kb[32,36) Vtb[40,44)
  //              part0[44,60) stat0[60,60.5) stat1[61,61.5)
  //  [64,112Mi)  QKVf (fp32) -> Wpb[64,96) after rope2/vtrans2; part1[96,112)
  short* Xb  = (short*)(ws);
  short* Wab = (short*)(ws + (16u << 20));
  short* Qb  = (short*)(ws + (16u << 20));
  short* Kb  = (short*)(ws + (32u << 20));
  short* Vtb = (short*)(ws + (40u << 20));
  short* Pt0 = (short*)(ws + (44u << 20));
  float2* St0 = (float2*)(ws + (60u << 20));
  float2* St1 = (float2*)(ws + (61u << 20));
  float* QKVf = (float*)(ws + (64u << 20));
  short* Wpb = (short*)(ws + (64u << 20));
  short* Pt1 = (short*)(ws + (96u << 20));
  short* AO  = Xb;

  const int nX = S_LEN * HDIM;
  const int nWa = QKVD * HDIM;
  const int nWp = HDIM * HDIM;

  hipFuncSetAttribute(reinterpret_cast<const void*>(gemm8p<384>),
                      hipFuncAttributeMaxDynamicSharedMemorySize, 131072);
  hipFuncSetAttribute(reinterpret_cast<const void*>(gemm8p<256>),
                      hipFuncAttributeMaxDynamicSharedMemorySize, 98304);

  cvt_kernel<<<nX / 1024, 256, 0, stream>>>(hidden, Xb, nX);
  cvt_kernel<<<nWa / 1024, 256, 0, stream>>>(w_attn, Wab, nWa);
  gemm8p<384><<<256, 512, 131072, stream>>>(Xb, Wab, QKVf, S_LEN, QKVD, HDIM);
  rope2_kernel<<<(S_LEN * NKVH * 5 * 64) / 256, 256, 0, stream>>>(QKVf, rcos, rsin, Qb, Kb);
  vtrans2_kernel<<<dim3(S_LEN / 64, HD / 64, NKVH), 256, 0, stream>>>(QKVf, Vtb);
  cvt_kernel<<<nWp / 1024, 256, 0, stream>>>(w_proj, Wpb, nWp);
  attn_kernel<<<dim3(NKVH, 64, 2), 256, 0, stream>>>(Qb, Kb, Vtb, Pt0, Pt1, St0, St1);
  combine_kernel<<<(NHEAD * S_LEN * HD / 8) / 256, 256, 0, stream>>>(Pt0, Pt1, St0, St1, AO);
  gemm8p<256><<<256, 512, 98304, stream>>>(AO, Wpb, out, S_LEN, HDIM, HDIM);
}

// Round 13
// 331.966 us; speedup vs baseline: 1.6490x; 1.0437x over previous
//
#include <hip/hip_runtime.h>
#include <cstdint>
#include <cstddef>

typedef __attribute__((ext_vector_type(4))) float f32x4;
typedef __attribute__((ext_vector_type(8))) short bf16x8;

#define S_LEN 2048
#define HDIM 4096
#define QKVD 6144
#define NHEAD 32
#define NKVH 8
#define HD 128
// Q pre-scaled by ATT_SCALE * log2(e): softmax runs in exp2 domain
#define QPRE 0.12751744631123533f

// fp32 -> bf16 RNE (finite inputs only)
__device__ __forceinline__ short f2bf(float f) {
  unsigned int u = __float_as_uint(f);
  u += 0x7FFFu + ((u >> 16) & 1u);
  return (short)(u >> 16);
}
__device__ __forceinline__ float bf2f(short s) {
  return __uint_as_float((unsigned int)(unsigned short)s << 16);
}

// async global->LDS, 16B per lane. LDS dest = wave-uniform base + lane*16.
__device__ __forceinline__ void gl_lds16(const short* g, short* l) {
  __builtin_amdgcn_global_load_lds((const __attribute__((address_space(1))) void*)g,
                                   (__attribute__((address_space(3))) void*)l,
                                   16, 0, 0);
}

template<int N> __device__ __forceinline__ void vmw() {
  if constexpr (N == 0) asm volatile("s_waitcnt vmcnt(0)" ::: "memory");
  else if constexpr (N == 1) asm volatile("s_waitcnt vmcnt(1)" ::: "memory");
  else if constexpr (N == 2) asm volatile("s_waitcnt vmcnt(2)" ::: "memory");
  else if constexpr (N == 3) asm volatile("s_waitcnt vmcnt(3)" ::: "memory");
  else if constexpr (N == 4) asm volatile("s_waitcnt vmcnt(4)" ::: "memory");
  // N==99: no wait
}

// fused fp32->bf16 conversion over up to three buffers (one launch)
__global__ void cvt3_kernel(const float* __restrict__ a, short* __restrict__ oa, int na,
                            const float* __restrict__ b, short* __restrict__ ob, int nb,
                            const float* __restrict__ c, short* __restrict__ oc, int nc) {
  int i = (blockIdx.x * blockDim.x + threadIdx.x) * 4;
  const float* src; short* dst;
  if (i < na) { src = a + i; dst = oa + i; }
  else if (i < na + nb) { src = b + (i - na); dst = ob + (i - na); }
  else if (i < na + nb + nc) { src = c + (i - na - nb); dst = oc + (i - na - nb); }
  else return;
  const float4 v = *reinterpret_cast<const float4*>(src);
  short4 o;
  o.x = f2bf(v.x); o.y = f2bf(v.y); o.z = f2bf(v.z); o.w = f2bf(v.w);
  *reinterpret_cast<short4*>(dst) = o;
}

// ---------------------------------------------------------------------------
// 4-phase deep-pipelined GEMM, snake phase order with register-held frags:
//   ph0 (0,0): load A0,B0   ph1 (0,1): hold A0, load B1
//   ph2 (1,1): load A1, hold B1   ph3 (1,0): hold A1, re-read B0
// A LDS-read once per tile (was 2x). Stage units issued in consume order
// A0,B0,B1,A1 (per-thread issues 1,NQ,NQ,1). Ordered-queue vmcnt ledger:
// steady (2, NQ+1, none, NQ+1), prologue NQ+1, tail (1,0,none,none). Every
// region's first ds_read is preceded by an all-waves vmcnt+barrier covering
// it; stages always write the opposite LDS buffer (no WAR).
// ---------------------------------------------------------------------------
#define PHASE(MH, NH, LOADA, LOADB, VM, STAGE) { \
    if (LOADA) { const short* bA = lA + buf * ATILE; \
      _Pragma("unroll") for (int m = 0; m < 2; ++m) { \
        int row = wm * 64 + (MH) * 32 + m * 16 + l15; \
        _Pragma("unroll") for (int kk = 0; kk < 2; ++kk) { \
          int slot = ((kk << 2) + l4) ^ (row & 7); \
          afH[m][kk] = *reinterpret_cast<const bf16x8*>(bA + row * 64 + slot * 8); } } } \
    if (LOADB) { const short* bB = lB + buf * BTILE; \
      _Pragma("unroll") for (int n = 0; n < NQ; ++n) { \
        int row = wn * (BN >> 2) + n * 32 + (NH) * 16 + l15; \
        _Pragma("unroll") for (int kk = 0; kk < 2; ++kk) { \
          int slot = ((kk << 2) + l4) ^ (row & 7); \
          bfH[n][kk] = *reinterpret_cast<const bf16x8*>(bB + row * 64 + slot * 8); } } } \
    STAGE; \
    vmw<(VM)>(); \
    __builtin_amdgcn_s_barrier(); \
    __builtin_amdgcn_sched_barrier(0); \
    __builtin_amdgcn_s_setprio(1); \
    _Pragma("unroll") for (int m = 0; m < 2; ++m) \
      _Pragma("unroll") for (int n = 0; n < NQ; ++n) \
        _Pragma("unroll") for (int kk = 0; kk < 2; ++kk) \
          acc[(MH) * 2 + m][(NH) * NQ + n] = __builtin_amdgcn_mfma_f32_16x16x32_bf16( \
              afH[m][kk], bfH[n][kk], acc[(MH) * 2 + m][(NH) * NQ + n], 0, 0, 0); \
    __builtin_amdgcn_s_setprio(0); }

template<int BN>
__global__ __launch_bounds__(512, 2) void gemm8p(const short* __restrict__ A,
                                                 const short* __restrict__ B,
                                                 float* __restrict__ C,
                                                 int M, int N, int K) {
  extern __shared__ short sm[];
  constexpr int NQ = BN / 128;
  constexpr int ATILE = 128 * 64;
  constexpr int BTILE = BN * 64;
  const int tid = threadIdx.x;
  const int wv = tid >> 6, lane = tid & 63;
  const int wm = wv >> 2, wn = wv & 3;
  const int l15 = lane & 15, l4 = lane >> 4;
  const int nbn = N / BN;
  const int nwg = gridDim.x;
  const int bid = blockIdx.x;
  const int sbid = (bid & 7) * (nwg >> 3) + (bid >> 3);  // XCD-contiguous (nwg%8==0)
  const int tm = (sbid / nbn) * 128, tn = (sbid % nbn) * BN;
  short* lA = sm;
  short* lB = sm + 2 * ATILE;
  (void)M;

  f32x4 acc[4][2 * NQ] = {};
  bf16x8 afH[2][2], bfH[NQ][2];

  auto stageA = [&](int k0, int bufi, int sel) {
    short* dst = lA + bufi * ATILE;
    int rowIdx = tid >> 3;
    int row = (rowIdx >> 5) * 64 + sel * 32 + (rowIdx & 31);
    int slot = tid & 7;
    gl_lds16(A + (size_t)(tm + row) * K + k0 + ((slot ^ (row & 7)) << 3),
             dst + row * 64 + slot * 8);
  };
  auto stageB = [&](int k0, int bufi, int par) {
    short* dst = lB + bufi * BTILE;
#pragma unroll
    for (int j = 0; j < NQ; ++j) {
      int rowIdx = (tid >> 3) + j * 64;
      int row = (rowIdx >> 4) * 32 + par * 16 + (rowIdx & 15);
      int slot = tid & 7;
      gl_lds16(B + (size_t)(tn + row) * K + k0 + ((slot ^ (row & 7)) << 3),
               dst + row * 64 + slot * 8);
    }
  };

  // prologue: tile 0, issue order = consume order
  stageA(0, 0, 0);
  stageB(0, 0, 0);
  stageB(0, 0, 1);
  stageA(0, 0, 1);
  vmw<NQ + 1>();
  __builtin_amdgcn_s_barrier();
  __builtin_amdgcn_sched_barrier(0);

  const int KT = K >> 6;
  for (int t = 0; t < KT - 1; ++t) {
    const int buf = t & 1, nbuf = buf ^ 1, nk0 = (t + 1) << 6;
    PHASE(0, 0, 1, 1, 2,      stageA(nk0, nbuf, 0))
    PHASE(0, 1, 0, 1, NQ + 1, stageB(nk0, nbuf, 0))
    PHASE(1, 1, 1, 0, 99,     stageB(nk0, nbuf, 1))
    PHASE(1, 0, 0, 1, NQ + 1, stageA(nk0, nbuf, 1))
  }
  {  // tail tile: no staging; drain progressively
    const int buf = (KT - 1) & 1;
    PHASE(0, 0, 1, 1, 1,  (void)0)
    PHASE(0, 1, 0, 1, 0,  (void)0)
    PHASE(1, 1, 1, 0, 99, (void)0)
    PHASE(1, 0, 0, 1, 99, (void)0)
  }
#pragma unroll
  for (int mg = 0; mg < 4; ++mg)
#pragma unroll
    for (int NH = 0; NH < 2; ++NH)
#pragma unroll
      for (int n = 0; n < NQ; ++n)
#pragma unroll
        for (int r = 0; r < 4; ++r) {
          int row = tm + wm * 64 + mg * 16 + l4 * 4 + r;
          int col = tn + wn * (BN >> 2) + n * 32 + NH * 16 + l15;
          C[(size_t)row * N + col] = acc[mg][NH * NQ + n][r];
        }
}

// rope pass 2: one thread per (s,g,part,d<64) pair. Q pre-scaled by QPRE so
// attention softmax runs in the exp2 domain with no per-element scale.
__global__ void rope2_kernel(const float* __restrict__ qkv,
                             const float* __restrict__ cb,
                             const float* __restrict__ sb,
                             short* __restrict__ Q,
                             short* __restrict__ Kx) {
  int tid = blockIdx.x * blockDim.x + threadIdx.x;
  int dh = tid & 63;
  int t2 = tid >> 6;
  int part = t2 % 5;
  int t3 = t2 / 5;
  int g = t3 & 7;
  int s = t3 >> 3;
  const float* base = qkv + (size_t)s * QKVD + g * 768 + part * 128;
  float v1 = base[dh], v2 = base[dh + 64];
  float c = cb[s * HD + dh], sn = sb[s * HD + dh];
  float o1 = v1 * c - v2 * sn;
  float o2 = v2 * c + v1 * sn;
  if (part < 4) {
    o1 *= QPRE; o2 *= QPRE;
    short* dst = Q + ((size_t)(g * 4 + part) * S_LEN + s) * HD;
    dst[dh] = f2bf(o1);
    dst[dh + 64] = f2bf(o2);
  } else {
    short* dst = Kx + ((size_t)g * S_LEN + s) * HD;
    dst[dh] = f2bf(o1);
    dst[dh + 64] = f2bf(o2);
  }
}

// V region of qkv (fp32) -> Vt [NKVH][HD][S] bf16, 64x64 LDS tiles
__global__ __launch_bounds__(256) void vtrans2_kernel(const float* __restrict__ qkv,
                                                      short* __restrict__ Vt) {
  __shared__ short tile[64][72];
  const int kvh = blockIdx.z;
  const int s0 = blockIdx.x * 64, d0 = blockIdx.y * 64;
  const int t = threadIdx.x;
#pragma unroll
  for (int i = 0; i < 4; ++i) {
    int c = t + i * 256;
    int sl = c >> 4, dl = (c & 15) * 4;
    const float4 v = *reinterpret_cast<const float4*>(
        qkv + (size_t)(s0 + sl) * QKVD + kvh * 768 + 640 + d0 + dl);
    tile[sl][dl] = f2bf(v.x); tile[sl][dl + 1] = f2bf(v.y);
    tile[sl][dl + 2] = f2bf(v.z); tile[sl][dl + 3] = f2bf(v.w);
  }
  __syncthreads();
  short* Vtb = Vt + (size_t)kvh * HD * S_LEN;
#pragma unroll
  for (int i = 0; i < 2; ++i) {
    int dl = i * 32 + (t >> 3), sl = (t & 7) * 8;
    bf16x8 o;
#pragma unroll
    for (int j = 0; j < 8; ++j) o[j] = tile[sl + j][dl];
    *reinterpret_cast<bf16x8*>(Vtb + (size_t)(d0 + dl) * S_LEN + s0 + sl) = o;
  }
}

// flash attention v6: kv-split flash-decoding (unchanged from round 9, passing)
__global__ __launch_bounds__(256, 2) void attn_kernel(const short* __restrict__ Q,
                                                      const short* __restrict__ Kx,
                                                      const short* __restrict__ Vt,
                                                      short* __restrict__ part0,
                                                      short* __restrict__ part1,
                                                      float2* __restrict__ stat0,
                                                      float2* __restrict__ stat1) {
  __shared__ short lK[2 * 64 * 128];
  __shared__ unsigned int lPu[4 * 2 * 512];
  const int tt = threadIdx.x;
  const int w = tt >> 6, lane = tt & 63;
  const int l15 = lane & 15, l4 = lane >> 4;
  const int kvh = blockIdx.x;
  const int qt = 63 - blockIdx.y;
  const int z = blockIdx.z;
  const int h = kvh * 4 + w;
  short* pout = z ? part1 : part0;
  float2* sout = z ? stat1 : stat0;

  const int nkt = (qt >> 1) + 1;
  const int ts = (nkt + 1) >> 1;
  const int t0 = z ? ts : 0;
  const int t1 = z ? nkt : ts;

  f32x4 o[2][8] = {};
  float m_run[2] = {-1e30f, -1e30f};
  float lsum[2] = {0.f, 0.f};

  if (t0 < t1) {
    bf16x8 qf[2][4];
#pragma unroll
    for (int qa = 0; qa < 2; ++qa) {
      const short* qrow = Q + ((size_t)h * S_LEN + qt * 32 + qa * 16 + l15) * HD + l4 * 8;
#pragma unroll
      for (int fd = 0; fd < 4; ++fd)
        qf[qa][fd] = *reinterpret_cast<const bf16x8*>(qrow + fd * 32);
    }
    const short* Kb = Kx + (size_t)kvh * S_LEN * HD;
    const short* Vb = Vt + (size_t)kvh * HD * S_LEN;

    {
      const short* Kg = Kb + (size_t)(t0 * 64) * HD;
#pragma unroll
      for (int i = 0; i < 4; ++i) {
        int c = tt + i * 256, row = c >> 4, jj = (c & 15) ^ (row & 7);
        gl_lds16(Kg + (size_t)row * HD + jj * 8, lK + c * 8);
      }
    }
    __syncthreads();

    int cur = 0;
    for (int kt = t0; kt < t1; ++kt) {
      const int c0 = kt * 64;
      if (kt + 1 < t1) {
        const short* Kg = Kb + (size_t)(c0 + 64) * HD;
        short* dst = lK + (cur ^ 1) * (64 * 128);
#pragma unroll
        for (int i = 0; i < 4; ++i) {
          int c = tt + i * 256, row = c >> 4, jj = (c & 15) ^ (row & 7);
          gl_lds16(Kg + (size_t)row * HD + jj * 8, dst + c * 8);
        }
      }
      const short* src = lK + cur * (64 * 128);
      f32x4 sf[2][4] = {};
      __builtin_amdgcn_s_setprio(1);
#pragma unroll
      for (int n = 0; n < 4; ++n) {
        bf16x8 kf[4];
#pragma unroll
        for (int fd = 0; fd < 4; ++fd) {
          int row = n * 16 + l15, jp = (l4 + fd * 4) ^ (l15 & 7);
          kf[fd] = *reinterpret_cast<const bf16x8*>(src + row * 128 + jp * 8);
        }
#pragma unroll
        for (int fd = 0; fd < 4; ++fd) {
          sf[0][n] = __builtin_amdgcn_mfma_f32_16x16x32_bf16(kf[fd], qf[0][fd], sf[0][n], 0, 0, 0);
          sf[1][n] = __builtin_amdgcn_mfma_f32_16x16x32_bf16(kf[fd], qf[1][fd], sf[1][n], 0, 0, 0);
        }
      }
      __builtin_amdgcn_s_setprio(0);
      bf16x8 vreg[8][2];
#pragma unroll
      for (int fd = 0; fd < 8; ++fd) {
        const short* vrow = Vb + (size_t)(fd * 16 + l15) * S_LEN + c0 + l4 * 8;
        vreg[fd][0] = *reinterpret_cast<const bf16x8*>(vrow);
        vreg[fd][1] = *reinterpret_cast<const bf16x8*>(vrow + 32);
      }
      const bool lastt = (kt == nkt - 1);
#pragma unroll
      for (int qa = 0; qa < 2; ++qa) {
        if (lastt) {  // wave-uniform: only the diagonal tile pays for masking
          const int qrow_g = qt * 32 + qa * 16 + l15;
#pragma unroll
          for (int n = 0; n < 4; ++n)
#pragma unroll
            for (int r = 0; r < 4; ++r)
              if ((c0 + n * 16 + l4 * 4 + r) > qrow_g) sf[qa][n][r] = -1e30f;
        }
        float mx = sf[qa][0][0];
#pragma unroll
        for (int n = 0; n < 4; ++n)
#pragma unroll
          for (int r = 0; r < 4; ++r) mx = fmaxf(mx, sf[qa][n][r]);
        mx = fmaxf(mx, __shfl_xor(mx, 16, 64));
        mx = fmaxf(mx, __shfl_xor(mx, 32, 64));
        float mnew = fmaxf(m_run[qa], mx);
        float alpha = exp2f(m_run[qa] - mnew);
        m_run[qa] = mnew;
        float ps = 0.f;
#pragma unroll
        for (int n = 0; n < 4; ++n)
#pragma unroll
          for (int r = 0; r < 4; ++r) {
            float e = exp2f(sf[qa][n][r] - mnew);
            sf[qa][n][r] = e;
            ps += e;
          }
        lsum[qa] = lsum[qa] * alpha + ps;
#pragma unroll
        for (int n = 0; n < 4; ++n)
#pragma unroll
          for (int rp = 0; rp < 2; ++rp) {
            unsigned int pkv =
                ((unsigned int)(unsigned short)f2bf(sf[qa][n][rp * 2 + 1]) << 16) |
                (unsigned short)f2bf(sf[qa][n][rp * 2]);
            int kv5 = ((n & 1) << 4) + l4 * 4 + rp * 2;
            lPu[w * 1024 + qa * 512 + ((n >> 1) << 8) +
                (l15 + ((kv5 >> 3) << 4)) * 4 + ((kv5 & 7) >> 1)] = pkv;
          }
        float aO[4];
#pragma unroll
        for (int r = 0; r < 4; ++r) aO[r] = __shfl(alpha, l4 * 4 + r, 64);
#pragma unroll
        for (int fd = 0; fd < 8; ++fd) {
          o[qa][fd][0] *= aO[0]; o[qa][fd][1] *= aO[1];
          o[qa][fd][2] *= aO[2]; o[qa][fd][3] *= aO[3];
        }
      }
      asm volatile("s_waitcnt lgkmcnt(0)" ::: "memory");
      bf16x8 pf[2][2];
#pragma unroll
      for (int qa = 0; qa < 2; ++qa)
#pragma unroll
        for (int p = 0; p < 2; ++p)
          pf[qa][p] = *reinterpret_cast<const bf16x8*>(
              (const short*)lPu + (w * 1024 + qa * 512 + p * 256 + lane * 4) * 2);
      __builtin_amdgcn_s_setprio(1);
#pragma unroll
      for (int fd = 0; fd < 8; ++fd) {
        o[0][fd] = __builtin_amdgcn_mfma_f32_16x16x32_bf16(pf[0][0], vreg[fd][0], o[0][fd], 0, 0, 0);
        o[0][fd] = __builtin_amdgcn_mfma_f32_16x16x32_bf16(pf[0][1], vreg[fd][1], o[0][fd], 0, 0, 0);
        o[1][fd] = __builtin_amdgcn_mfma_f32_16x16x32_bf16(pf[1][0], vreg[fd][0], o[1][fd], 0, 0, 0);
        o[1][fd] = __builtin_amdgcn_mfma_f32_16x16x32_bf16(pf[1][1], vreg[fd][1], o[1][fd], 0, 0, 0);
      }
      __builtin_amdgcn_s_setprio(0);
      __syncthreads();
      cur ^= 1;
    }
  }
  // epilogue: reduce lsum, write stats + unnormalized partial O
#pragma unroll
  for (int qa = 0; qa < 2; ++qa) {
    float s = lsum[qa];
    s += __shfl_xor(s, 16, 64);
    s += __shfl_xor(s, 32, 64);
    if (l4 == 0)
      sout[(size_t)h * S_LEN + qt * 32 + qa * 16 + l15] = make_float2(m_run[qa], s);
#pragma unroll
    for (int fd = 0; fd < 8; ++fd)
#pragma unroll
      for (int r = 0; r < 4; ++r)
        pout[((size_t)h * S_LEN + qt * 32 + qa * 16 + l4 * 4 + r) * HD + fd * 16 + l15] =
            f2bf(o[qa][fd][r]);
  }
}

// merge the two kv-split partials -> AO [S][NH*HD]
__global__ __launch_bounds__(256) void combine_kernel(const short* __restrict__ p0,
                                                      const short* __restrict__ p1,
                                                      const float2* __restrict__ st0,
                                                      const float2* __restrict__ st1,
                                                      short* __restrict__ AO) {
  int idx = (blockIdx.x * 256 + threadIdx.x) * 8;  // over NH*S*HD
  int h = idx >> 18;                 // S*HD = 2^18
  int rem = idx & ((1 << 18) - 1);
  int s = rem >> 7, d = rem & 127;
  float2 a = st0[(size_t)h * S_LEN + s];
  float2 b = st1[(size_t)h * S_LEN + s];
  float M = fmaxf(a.x, b.x);
  float w0 = exp2f(a.x - M), w1 = exp2f(b.x - M);
  float inv = 1.f / (a.y * w0 + b.y * w1);
  w0 *= inv; w1 *= inv;
  bf16x8 v0 = *reinterpret_cast<const bf16x8*>(p0 + idx);
  bf16x8 v1 = *reinterpret_cast<const bf16x8*>(p1 + idx);
  bf16x8 ov;
#pragma unroll
  for (int j = 0; j < 8; ++j)
    ov[j] = f2bf(bf2f(v0[j]) * w0 + bf2f(v1[j]) * w1);
  *reinterpret_cast<bf16x8*>(AO + (size_t)s * HDIM + h * HD + d) = ov;
}

extern "C" void kernel_launch(void* const* d_in, const int* in_sizes, int n_in,
                              void* d_out, int out_size, void* d_ws, size_t ws_size,
                              hipStream_t stream) {
  const float* hidden = (const float*)d_in[0];
  const float* w_attn = (const float*)d_in[1];
  const float* w_proj = (const float*)d_in[2];
  const float* rcos = (const float*)d_in[3];
  const float* rsin = (const float*)d_in[4];
  float* out = (float*)d_out;
  char* ws = (char*)d_ws;

  // workspace layout (overlaid, 112 MiB):
  //  [0,16Mi)    Xb (bf16 X)  -> dead after gemm1 -> AO (combine output)
  //  [16,64Mi)   Wab (bf16 w_attn) -> after gemm1: Qb[16,32) Kb[32,36)
  //              Vtb[36,40) St0[40,40.5) St1[41,41.5) Pt0[44,60)
  //  [64,112Mi)  QKVf (fp32, live gemm1->vtrans2) -> then Pt1[64,80) Wpb[80,112)
  short* Xb  = (short*)(ws);
  short* Wab = (short*)(ws + (16u << 20));
  short* Qb  = (short*)(ws + (16u << 20));
  short* Kb  = (short*)(ws + (32u << 20));
  short* Vtb = (short*)(ws + (36u << 20));
  float2* St0 = (float2*)(ws + (40u << 20));
  float2* St1 = (float2*)(ws + (41u << 20));
  short* Pt0 = (short*)(ws + (44u << 20));
  float* QKVf = (float*)(ws + (64u << 20));
  short* Pt1 = (short*)(ws + (64u << 20));   // written after QKVf is dead
  short* Wpb = (short*)(ws + (80u << 20));   // converted after QKVf is dead
  short* AO  = Xb;

  const int nX = S_LEN * HDIM;       // 8388608
  const int nWa = QKVD * HDIM;       // 25165824
  const int nWp = HDIM * HDIM;       // 16777216

  hipFuncSetAttribute(reinterpret_cast<const void*>(gemm8p<384>),
                      hipFuncAttributeMaxDynamicSharedMemorySize, 131072);
  hipFuncSetAttribute(reinterpret_cast<const void*>(gemm8p<256>),
                      hipFuncAttributeMaxDynamicSharedMemorySize, 98304);

  cvt3_kernel<<<(nX + nWa) / 1024, 256, 0, stream>>>(
      hidden, Xb, nX, w_attn, Wab, nWa, (const float*)nullptr, (short*)nullptr, 0);
  gemm8p<384><<<256, 512, 131072, stream>>>(Xb, Wab, QKVf, S_LEN, QKVD, HDIM);
  rope2_kernel<<<(S_LEN * NKVH * 5 * 64) / 256, 256, 0, stream>>>(QKVf, rcos, rsin, Qb, Kb);
  vtrans2_kernel<<<dim3(S_LEN / 64, HD / 64, NKVH), 256, 0, stream>>>(QKVf, Vtb);
  cvt3_kernel<<<nWp / 1024, 256, 0, stream>>>(
      w_proj, Wpb, nWp, (const float*)nullptr, (short*)nullptr, 0,
      (const float*)nullptr, (short*)nullptr, 0);
  attn_kernel<<<dim3(NKVH, 64, 2), 256, 0, stream>>>(Qb, Kb, Vtb, Pt0, Pt1, St0, St1);
  combine_kernel<<<(NHEAD * S_LEN * HD / 8) / 256, 256, 0, stream>>>(Pt0, Pt1, St0, St1, AO);
  gemm8p<256><<<256, 512, 98304, stream>>>(AO, Wpb, out, S_LEN, HDIM, HDIM);
}